// Round 1
// baseline (550.454 us; speedup 1.0000x reference)
//
#include <hip/hip_runtime.h>
#include <cstdint>
#include <cmath>

typedef unsigned short u16;
typedef unsigned long long u64;
typedef __bf16 bf16x8 __attribute__((ext_vector_type(8)));
typedef float f32x4 __attribute__((ext_vector_type(4)));

#define AS1 __attribute__((address_space(1)))
#define AS3 __attribute__((address_space(3)))

static constexpr int DM = 1024, DFF = 4096, SS = 2048, HH = 16, HD = 64, TT = 4096;

__device__ __forceinline__ u16 f2bf(float f) {
  union { float f; unsigned u; } c; c.f = f;
  unsigned r = c.u + 0x7fffu + ((c.u >> 16) & 1u);
  return (u16)(r >> 16);
}

__device__ __forceinline__ void gload_lds16(const void* g, void* l) {
  __builtin_amdgcn_global_load_lds((AS1 void*)g, (AS3 void*)l, 16, 0, 0);
}

// ---------------- cast fp32 -> bf16 (vectorized) ----------------
__global__ __launch_bounds__(256) void k_cast(const float* __restrict__ in,
                                              u16* __restrict__ out, int n4) {
  int i = blockIdx.x * 256 + threadIdx.x;
  if (i < n4) {
    float4 v = ((const float4*)in)[i];
    u64 pk = (u64)f2bf(v.x) | ((u64)f2bf(v.y) << 16) |
             ((u64)f2bf(v.z) << 32) | ((u64)f2bf(v.w) << 48);
    ((u64*)out)[i] = pk;
  }
}

// ------------- transpose+cast: in fp32 [R][C] -> out bf16 [C][R] -------------
__global__ __launch_bounds__(256) void k_transpose_cast(const float* __restrict__ in,
                                                        u16* __restrict__ out,
                                                        int R, int C) {
  __shared__ u16 tile[32][33];
  const int cb = blockIdx.x * 32, rb = blockIdx.y * 32;
  const int tx = threadIdx.x & 31;
  const int ty = threadIdx.x >> 5;  // 0..7
#pragma unroll
  for (int i = 0; i < 4; i++) {
    int r = ty + i * 8;
    tile[r][tx] = f2bf(in[(size_t)(rb + r) * C + cb + tx]);
  }
  __syncthreads();
#pragma unroll
  for (int i = 0; i < 4; i++) {
    int r2 = ty + i * 8;
    out[(size_t)(cb + r2) * R + rb + tx] = tile[tx][r2];
  }
}

// ---------------- bf16 MFMA GEMM: C = A[M,K] * Bt[N,K]^T + bias ----------------
enum { EPI_F32 = 0, EPI_GELU = 1, EPI_QKV = 2, EPI_VT = 3 };

template <int EPI>
__global__ __launch_bounds__(256) void k_gemm(const u16* __restrict__ A,
                                              const u16* __restrict__ Bt,
                                              const float* __restrict__ bias,
                                              void* __restrict__ Cout,
                                              int M, int N, int K) {
  __shared__ __align__(16) u16 Alds[128 * 32];
  __shared__ __align__(16) u16 Blds[128 * 32];
  const int tid = threadIdx.x;
  const int wid = tid >> 6, lane = tid & 63;
  const int lrow = lane & 15, lgrp = lane >> 4;
  const int mrow = blockIdx.y * 128, ncol = blockIdx.x * 128;
  const int wr = wid >> 1, wc = wid & 1;

  f32x4 acc[4][4];
#pragma unroll
  for (int m = 0; m < 4; m++)
#pragma unroll
    for (int n = 0; n < 4; n++) acc[m][n] = (f32x4){0.f, 0.f, 0.f, 0.f};

  const int r0 = tid >> 2;           // 0..63
  const int c0 = (tid & 3) * 8;      // k element offset
  const u16* aBase = A + (size_t)(mrow + r0) * K + c0;
  const u16* bBase = Bt + (size_t)(ncol + r0) * K + c0;
  char* la = (char*)Alds + wid * 1024;  // wave-uniform LDS dest
  char* lb = (char*)Blds + wid * 1024;

  for (int k0 = 0; k0 < K; k0 += 32) {
    gload_lds16(aBase + k0, la);
    gload_lds16(aBase + (size_t)64 * K + k0, la + 4096);
    gload_lds16(bBase + k0, lb);
    gload_lds16(bBase + (size_t)64 * K + k0, lb + 4096);
    __syncthreads();
    bf16x8 af[4], bfr[4];
#pragma unroll
    for (int m = 0; m < 4; m++)
      af[m] = *(const bf16x8*)&Alds[(wr * 64 + m * 16 + lrow) * 32 + lgrp * 8];
#pragma unroll
    for (int n = 0; n < 4; n++)
      bfr[n] = *(const bf16x8*)&Blds[(wc * 64 + n * 16 + lrow) * 32 + lgrp * 8];
#pragma unroll
    for (int m = 0; m < 4; m++)
#pragma unroll
      for (int n = 0; n < 4; n++)
        acc[m][n] = __builtin_amdgcn_mfma_f32_16x16x32_bf16(af[m], bfr[n], acc[m][n], 0, 0, 0);
    __syncthreads();
  }

#pragma unroll
  for (int m = 0; m < 4; m++) {
#pragma unroll
    for (int n = 0; n < 4; n++) {
      const int row0 = mrow + wr * 64 + m * 16 + lgrp * 4;
      const int col = ncol + wc * 64 + n * 16 + lrow;
      const float bv = bias[col];
      f32x4 v = acc[m][n];
      if constexpr (EPI == EPI_F32) {
        float* C = (float*)Cout;
#pragma unroll
        for (int r = 0; r < 4; r++) C[(size_t)(row0 + r) * N + col] = v[r] + bv;
      } else if constexpr (EPI == EPI_GELU) {
        u16* C = (u16*)Cout;
#pragma unroll
        for (int r = 0; r < 4; r++) {
          float xg = v[r] + bv;
          float gl = 0.5f * xg * (1.0f + erff(xg * 0.70710678118654752f));
          C[(size_t)(row0 + r) * N + col] = f2bf(gl);
        }
      } else if constexpr (EPI == EPI_QKV) {
        u16* C = (u16*)Cout;
        const int h = col >> 6, d = col & 63;
#pragma unroll
        for (int r = 0; r < 4; r++) {
          const int row = row0 + r;
          const int b = row >> 11, s = row & 2047;
          C[((size_t)(b * HH + h) * SS + s) * HD + d] = f2bf(v[r] + bv);
        }
      } else {  // EPI_VT: write V^T [B,H,hd,S]
        u16* C = (u16*)Cout;
        const int h = col >> 6, d = col & 63;
        const int b = row0 >> 11, s = row0 & 2047;
        u64 pk = (u64)f2bf(v[0] + bv) | ((u64)f2bf(v[1] + bv) << 16) |
                 ((u64)f2bf(v[2] + bv) << 32) | ((u64)f2bf(v[3] + bv) << 48);
        *(u64*)&C[((size_t)(b * HH + h) * HD + d) * SS + s] = pk;
      }
    }
  }
}

// ---------------- flash attention fwd ----------------
// Q,K: [B,H,S,hd] bf16; Vt: [B,H,hd,S] bf16; O: [T, D] bf16
__global__ __launch_bounds__(256) void k_attn(const u16* __restrict__ Q,
                                              const u16* __restrict__ K,
                                              const u16* __restrict__ Vt,
                                              u16* __restrict__ O) {
  __shared__ __align__(16) u16 plds[4][16 * 32];
  const int tid = threadIdx.x, wid = tid >> 6, lane = tid & 63;
  const int lrow = lane & 15, lgrp = lane >> 4;
  const int blk = blockIdx.x;
  const int bh = blk >> 5;        // b*16+h
  const int qblk = blk & 31;
  const int qbase = qblk * 64 + wid * 16;
  const u16* Qh = Q + (size_t)bh * SS * HD;
  const u16* Kh = K + (size_t)bh * SS * HD;
  const u16* Vh = Vt + (size_t)bh * HD * SS;

  bf16x8 qf[2];
  qf[0] = *(const bf16x8*)&Qh[(size_t)(qbase + lrow) * HD + lgrp * 8];
  qf[1] = *(const bf16x8*)&Qh[(size_t)(qbase + lrow) * HD + 32 + lgrp * 8];

  float m_r[4], l_r[4];
  f32x4 oacc[4];
#pragma unroll
  for (int r = 0; r < 4; r++) { m_r[r] = -1e30f; l_r[r] = 0.f; }
#pragma unroll
  for (int n = 0; n < 4; n++) oacc[n] = (f32x4){0.f, 0.f, 0.f, 0.f};

  for (int kv = 0; kv < SS; kv += 32) {
    f32x4 sc[2];
#pragma unroll
    for (int j = 0; j < 2; j++) {
      const u16* Krow = &Kh[(size_t)(kv + j * 16 + lrow) * HD + lgrp * 8];
      bf16x8 kf0 = *(const bf16x8*)Krow;
      bf16x8 kf1 = *(const bf16x8*)(Krow + 32);
      f32x4 z = (f32x4){0.f, 0.f, 0.f, 0.f};
      z = __builtin_amdgcn_mfma_f32_16x16x32_bf16(qf[0], kf0, z, 0, 0, 0);
      z = __builtin_amdgcn_mfma_f32_16x16x32_bf16(qf[1], kf1, z, 0, 0, 0);
      sc[j] = z;
    }
    const float scale = 0.125f;  // 1/sqrt(64)
    float alpha[4];
    u16 pb[2][4];
#pragma unroll
    for (int r = 0; r < 4; r++) {
      float s0 = sc[0][r] * scale, s1 = sc[1][r] * scale;
      float v = fmaxf(s0, s1);
#pragma unroll
      for (int msk = 1; msk < 16; msk <<= 1) v = fmaxf(v, __shfl_xor(v, msk));
      float mn = fmaxf(m_r[r], v);
      alpha[r] = __expf(m_r[r] - mn);
      m_r[r] = mn;
      float p0 = __expf(s0 - mn), p1 = __expf(s1 - mn);
      pb[0][r] = f2bf(p0);
      pb[1][r] = f2bf(p1);
      float ps = p0 + p1;
#pragma unroll
      for (int msk = 1; msk < 16; msk <<= 1) ps += __shfl_xor(ps, msk);
      l_r[r] = l_r[r] * alpha[r] + ps;
    }
#pragma unroll
    for (int n = 0; n < 4; n++)
#pragma unroll
      for (int r = 0; r < 4; r++) oacc[n][r] *= alpha[r];
    // P -> per-wave LDS (transpose to A-fragment layout)
#pragma unroll
    for (int j = 0; j < 2; j++)
#pragma unroll
      for (int r = 0; r < 4; r++)
        plds[wid][(lgrp * 4 + r) * 32 + j * 16 + lrow] = pb[j][r];
    asm volatile("s_waitcnt lgkmcnt(0)" ::: "memory");
    bf16x8 ap = *(const bf16x8*)&plds[wid][lrow * 32 + lgrp * 8];
#pragma unroll
    for (int n = 0; n < 4; n++) {
      bf16x8 bv = *(const bf16x8*)&Vh[(size_t)(n * 16 + lrow) * SS + kv + lgrp * 8];
      oacc[n] = __builtin_amdgcn_mfma_f32_16x16x32_bf16(ap, bv, oacc[n], 0, 0, 0);
    }
  }
  const int b = bh >> 4, h = bh & 15;
#pragma unroll
  for (int n = 0; n < 4; n++) {
#pragma unroll
    for (int r = 0; r < 4; r++) {
      const int q = qbase + lgrp * 4 + r;
      float val = oacc[n][r] / l_r[r];
      O[((size_t)(b * SS + q)) * DM + h * HD + n * 16 + lrow] = f2bf(val);
    }
  }
}

// ---------------- fused residual + layernorm ----------------
template <bool WB>
__global__ __launch_bounds__(256) void k_res_ln(const float* __restrict__ X,
                                                const float* __restrict__ Y,
                                                const float* __restrict__ gw,
                                                const float* __restrict__ bw,
                                                float* __restrict__ outf,
                                                u16* __restrict__ outb) {
  const int row = blockIdx.x, t = threadIdx.x;
  const float4 xv = ((const float4*)(X + (size_t)row * DM))[t];
  const float4 yv = ((const float4*)(Y + (size_t)row * DM))[t];
  float v0 = xv.x + yv.x, v1 = xv.y + yv.y, v2 = xv.z + yv.z, v3 = xv.w + yv.w;
  float s = v0 + v1 + v2 + v3;
  float s2 = v0 * v0 + v1 * v1 + v2 * v2 + v3 * v3;
#pragma unroll
  for (int off = 32; off >= 1; off >>= 1) {
    s += __shfl_down(s, off);
    s2 += __shfl_down(s2, off);
  }
  __shared__ float ps[4], ps2[4];
  const int wid = t >> 6, lane = t & 63;
  if (lane == 0) { ps[wid] = s; ps2[wid] = s2; }
  __syncthreads();
  const float ts = ps[0] + ps[1] + ps[2] + ps[3];
  const float ts2 = ps2[0] + ps2[1] + ps2[2] + ps2[3];
  const float mu = ts * (1.f / 1024.f);
  const float rs = rsqrtf(ts2 * (1.f / 1024.f) - mu * mu + 1e-5f);
  const float4 g4 = ((const float4*)gw)[t];
  const float4 b4 = ((const float4*)bw)[t];
  float o0 = (v0 - mu) * rs * g4.x + b4.x;
  float o1 = (v1 - mu) * rs * g4.y + b4.y;
  float o2 = (v2 - mu) * rs * g4.z + b4.z;
  float o3 = (v3 - mu) * rs * g4.w + b4.w;
  ((float4*)(outf + (size_t)row * DM))[t] = make_float4(o0, o1, o2, o3);
  if constexpr (WB) {
    u64 pk = (u64)f2bf(o0) | ((u64)f2bf(o1) << 16) | ((u64)f2bf(o2) << 32) |
             ((u64)f2bf(o3) << 48);
    ((u64*)(outb + (size_t)row * DM))[t] = pk;
  }
}

extern "C" void kernel_launch(void* const* d_in, const int* in_sizes, int n_in,
                              void* d_out, int out_size, void* d_ws, size_t ws_size,
                              hipStream_t stream) {
  const float* x = (const float*)d_in[0];
  const float* Wq = (const float*)d_in[1];
  const float* bq = (const float*)d_in[2];
  const float* Wk = (const float*)d_in[3];
  const float* bk = (const float*)d_in[4];
  const float* Wv = (const float*)d_in[5];
  const float* bv = (const float*)d_in[6];
  const float* Wo = (const float*)d_in[7];
  const float* bo = (const float*)d_in[8];
  const float* g1 = (const float*)d_in[9];
  const float* b1 = (const float*)d_in[10];
  const float* g2 = (const float*)d_in[11];
  const float* b2 = (const float*)d_in[12];
  const float* W1 = (const float*)d_in[13];
  const float* bf1 = (const float*)d_in[14];
  const float* W2 = (const float*)d_in[15];
  const float* bf2 = (const float*)d_in[16];
  float* out = (float*)d_out;

  const size_t MB = (size_t)1 << 20;
  if (ws_size < 104 * MB) return;  // workspace layout needs 104 MB
  char* ws = (char*)d_ws;
  u16* WqT = (u16*)(ws + 0 * MB);
  u16* WkT = (u16*)(ws + 2 * MB);
  u16* WvT = (u16*)(ws + 4 * MB);
  u16* WoT = (u16*)(ws + 6 * MB);
  u16* W1T = (u16*)(ws + 8 * MB);   // [4096][1024]
  u16* W2T = (u16*)(ws + 16 * MB);  // [1024][4096]
  u16* xb = (u16*)(ws + 24 * MB);   // [T][D] bf16
  u16* Qb = (u16*)(ws + 32 * MB);   // [B,H,S,hd]
  u16* Kb = (u16*)(ws + 40 * MB);
  u16* Vt = (u16*)(ws + 48 * MB);   // [B,H,hd,S]
  u16* Ob = (u16*)(ws + 24 * MB);   // reuse xb (dead after QKV GEMMs)
  float* attn = (float*)(ws + 64 * MB);  // [T][D] f32
  float* hf = (float*)(ws + 32 * MB);    // reuse Q,K (dead after attn)
  u16* hb = (u16*)(ws + 48 * MB);        // reuse Vt
  u16* f1 = (u16*)(ws + 56 * MB);        // [T][DFF] bf16, 32MB (attn dead by then)
  float* ffn = (float*)(ws + 88 * MB);   // [T][D] f32

  k_cast<<<4096, 256, 0, stream>>>(x, xb, TT * DM / 4);
  k_transpose_cast<<<dim3(32, 32), 256, 0, stream>>>(Wq, WqT, DM, DM);
  k_transpose_cast<<<dim3(32, 32), 256, 0, stream>>>(Wk, WkT, DM, DM);
  k_transpose_cast<<<dim3(32, 32), 256, 0, stream>>>(Wv, WvT, DM, DM);
  k_transpose_cast<<<dim3(32, 32), 256, 0, stream>>>(Wo, WoT, DM, DM);
  k_transpose_cast<<<dim3(128, 32), 256, 0, stream>>>(W1, W1T, DM, DFF);
  k_transpose_cast<<<dim3(32, 128), 256, 0, stream>>>(W2, W2T, DFF, DM);

  k_gemm<EPI_QKV><<<dim3(8, 32), 256, 0, stream>>>(xb, WqT, bq, Qb, TT, DM, DM);
  k_gemm<EPI_QKV><<<dim3(8, 32), 256, 0, stream>>>(xb, WkT, bk, Kb, TT, DM, DM);
  k_gemm<EPI_VT><<<dim3(8, 32), 256, 0, stream>>>(xb, WvT, bv, Vt, TT, DM, DM);

  k_attn<<<1024, 256, 0, stream>>>(Qb, Kb, Vt, Ob);

  k_gemm<EPI_F32><<<dim3(8, 32), 256, 0, stream>>>(Ob, WoT, bo, attn, TT, DM, DM);
  k_res_ln<true><<<4096, 256, 0, stream>>>(x, attn, g1, b1, hf, hb);
  k_gemm<EPI_GELU><<<dim3(32, 32), 256, 0, stream>>>(hb, W1T, bf1, f1, TT, DFF, DM);
  k_gemm<EPI_F32><<<dim3(8, 32), 256, 0, stream>>>(f1, W2T, bf2, ffn, TT, DM, DFF);
  k_res_ln<false><<<4096, 256, 0, stream>>>(hf, ffn, g2, b2, out, nullptr);
}

// Round 2
// 440.336 us; speedup vs baseline: 1.2501x; 1.2501x over previous
//
#include <hip/hip_runtime.h>
#include <cstdint>
#include <cmath>

typedef unsigned short u16;
typedef unsigned int u32;
typedef unsigned long long u64;
typedef __bf16 bf16x8 __attribute__((ext_vector_type(8)));
typedef float f32x4 __attribute__((ext_vector_type(4)));
typedef float f32x16 __attribute__((ext_vector_type(16)));
typedef int v2i __attribute__((ext_vector_type(2)));

#define AS1 __attribute__((address_space(1)))
#define AS3 __attribute__((address_space(3)))

static constexpr int DM = 1024, DFF = 4096, SS = 2048, HH = 16, HD = 64, TT = 4096;

__device__ __forceinline__ u16 f2bf(float f) {
  union { float f; unsigned u; } c; c.f = f;
  unsigned r = c.u + 0x7fffu + ((c.u >> 16) & 1u);
  return (u16)(r >> 16);
}

__device__ __forceinline__ void gload_lds16(const void* g, void* l) {
  __builtin_amdgcn_global_load_lds((AS1 void*)g, (AS3 void*)l, 16, 0, 0);
}

__device__ __forceinline__ float exp2_(float x) {
#if __has_builtin(__builtin_amdgcn_exp2f)
  return __builtin_amdgcn_exp2f(x);
#else
  return exp2f(x);
#endif
}

__device__ __forceinline__ u32 cvt_pk_bf16(float lo, float hi) {
  u32 r;
  asm("v_cvt_pk_bf16_f32 %0, %1, %2" : "=v"(r) : "v"(lo), "v"(hi));
  return r;
}

// exchange across 32-lane halves: a' = {lo: a_lo, hi: b_lo}, b' = {lo: a_hi, hi: b_hi}
__device__ __forceinline__ void lane32_swap(u32& a, u32& b) {
#if __has_builtin(__builtin_amdgcn_permlane32_swap)
  v2i r = __builtin_amdgcn_permlane32_swap((int)a, (int)b, false, false);
  a = (u32)r.x;
  b = (u32)r.y;
#else
  u32 ta = (u32)__shfl_xor((int)a, 32);
  u32 tb = (u32)__shfl_xor((int)b, 32);
  bool hi = (threadIdx.x & 32) != 0;
  u32 na = hi ? tb : a;
  u32 nb = hi ? b : ta;
  a = na;
  b = nb;
#endif
}

__device__ __forceinline__ float cross32_reduce_max(float x) {
  u32 a = __float_as_uint(x), b = a;
  lane32_swap(a, b);
  return fmaxf(__uint_as_float(a), __uint_as_float(b));
}

__device__ __forceinline__ float cross32_reduce_sum(float x) {
  u32 a = __float_as_uint(x), b = a;
  lane32_swap(a, b);
  return __uint_as_float(a) + __uint_as_float(b);
}

// ---------------- cast fp32 -> bf16 (vectorized) ----------------
__global__ __launch_bounds__(256) void k_cast(const float* __restrict__ in,
                                              u16* __restrict__ out, int n4) {
  int i = blockIdx.x * 256 + threadIdx.x;
  if (i < n4) {
    float4 v = ((const float4*)in)[i];
    u64 pk = (u64)f2bf(v.x) | ((u64)f2bf(v.y) << 16) |
             ((u64)f2bf(v.z) << 32) | ((u64)f2bf(v.w) << 48);
    ((u64*)out)[i] = pk;
  }
}

// ------------- transpose+cast: in fp32 [R][C] -> out bf16 [C][R] -------------
__global__ __launch_bounds__(256) void k_transpose_cast(const float* __restrict__ in,
                                                        u16* __restrict__ out,
                                                        int R, int C) {
  __shared__ u16 tile[32][33];
  const int cb = blockIdx.x * 32, rb = blockIdx.y * 32;
  const int tx = threadIdx.x & 31;
  const int ty = threadIdx.x >> 5;  // 0..7
#pragma unroll
  for (int i = 0; i < 4; i++) {
    int r = ty + i * 8;
    tile[r][tx] = f2bf(in[(size_t)(rb + r) * C + cb + tx]);
  }
  __syncthreads();
#pragma unroll
  for (int i = 0; i < 4; i++) {
    int r2 = ty + i * 8;
    out[(size_t)(cb + r2) * R + rb + tx] = tile[tx][r2];
  }
}

// ---------------- bf16 MFMA GEMM: C = A[M,K] * Bt[N,K]^T + bias ----------------
enum { EPI_F32 = 0, EPI_GELU = 1, EPI_QKV = 2, EPI_VT = 3 };

template <int EPI>
__global__ __launch_bounds__(256) void k_gemm(const u16* __restrict__ A,
                                              const u16* __restrict__ Bt,
                                              const float* __restrict__ bias,
                                              void* __restrict__ Cout,
                                              int M, int N, int K) {
  __shared__ __align__(16) u16 Alds[128 * 32];
  __shared__ __align__(16) u16 Blds[128 * 32];
  const int tid = threadIdx.x;
  const int wid = tid >> 6, lane = tid & 63;
  const int lrow = lane & 15, lgrp = lane >> 4;
  const int mrow = blockIdx.y * 128, ncol = blockIdx.x * 128;
  const int wr = wid >> 1, wc = wid & 1;

  f32x4 acc[4][4];
#pragma unroll
  for (int m = 0; m < 4; m++)
#pragma unroll
    for (int n = 0; n < 4; n++) acc[m][n] = (f32x4){0.f, 0.f, 0.f, 0.f};

  const int r0 = tid >> 2;           // 0..63
  const int c0 = (tid & 3) * 8;      // k element offset
  const u16* aBase = A + (size_t)(mrow + r0) * K + c0;
  const u16* bBase = Bt + (size_t)(ncol + r0) * K + c0;
  char* la = (char*)Alds + wid * 1024;  // wave-uniform LDS dest
  char* lb = (char*)Blds + wid * 1024;

  for (int k0 = 0; k0 < K; k0 += 32) {
    gload_lds16(aBase + k0, la);
    gload_lds16(aBase + (size_t)64 * K + k0, la + 4096);
    gload_lds16(bBase + k0, lb);
    gload_lds16(bBase + (size_t)64 * K + k0, lb + 4096);
    __syncthreads();
    bf16x8 af[4], bfr[4];
#pragma unroll
    for (int m = 0; m < 4; m++)
      af[m] = *(const bf16x8*)&Alds[(wr * 64 + m * 16 + lrow) * 32 + lgrp * 8];
#pragma unroll
    for (int n = 0; n < 4; n++)
      bfr[n] = *(const bf16x8*)&Blds[(wc * 64 + n * 16 + lrow) * 32 + lgrp * 8];
#pragma unroll
    for (int m = 0; m < 4; m++)
#pragma unroll
      for (int n = 0; n < 4; n++)
        acc[m][n] = __builtin_amdgcn_mfma_f32_16x16x32_bf16(af[m], bfr[n], acc[m][n], 0, 0, 0);
    __syncthreads();
  }

#pragma unroll
  for (int m = 0; m < 4; m++) {
#pragma unroll
    for (int n = 0; n < 4; n++) {
      const int row0 = mrow + wr * 64 + m * 16 + lgrp * 4;
      const int col = ncol + wc * 64 + n * 16 + lrow;
      const float bv = bias[col];
      f32x4 v = acc[m][n];
      if constexpr (EPI == EPI_F32) {
        float* C = (float*)Cout;
#pragma unroll
        for (int r = 0; r < 4; r++) C[(size_t)(row0 + r) * N + col] = v[r] + bv;
      } else if constexpr (EPI == EPI_GELU) {
        u16* C = (u16*)Cout;
#pragma unroll
        for (int r = 0; r < 4; r++) {
          float xg = v[r] + bv;
          float gl = 0.5f * xg * (1.0f + erff(xg * 0.70710678118654752f));
          C[(size_t)(row0 + r) * N + col] = f2bf(gl);
        }
      } else if constexpr (EPI == EPI_QKV) {
        u16* C = (u16*)Cout;
        const int h = col >> 6, d = col & 63;
#pragma unroll
        for (int r = 0; r < 4; r++) {
          const int row = row0 + r;
          const int b = row >> 11, s = row & 2047;
          C[((size_t)(b * HH + h) * SS + s) * HD + d] = f2bf(v[r] + bv);
        }
      } else {  // EPI_VT: write V^T [B,H,hd,S]
        u16* C = (u16*)Cout;
        const int h = col >> 6, d = col & 63;
        const int b = row0 >> 11, s = row0 & 2047;
        u64 pk = (u64)f2bf(v[0] + bv) | ((u64)f2bf(v[1] + bv) << 16) |
                 ((u64)f2bf(v[2] + bv) << 32) | ((u64)f2bf(v[3] + bv) << 48);
        *(u64*)&C[((size_t)(b * HH + h) * HD + d) * SS + s] = pk;
      }
    }
  }
}

// ---------------- flash attention fwd, 32x32 swapped-operand structure ----------------
// Q,K: [B,H,S,hd] bf16; Vt: [B,H,hd,S] bf16; O: [T, DM] bf16
// Per warp: 32 q rows. S^T = K*Q^T (col=q lane-local), O^T = V^T*P (col=q lane-local).
// No LDS, no barriers; K/V direct from global (L2-resident); reg double-buffer.
__global__ __launch_bounds__(256) void k_attn(const u16* __restrict__ Q,
                                              const u16* __restrict__ K,
                                              const u16* __restrict__ Vt,
                                              u16* __restrict__ O) {
  const int tid = threadIdx.x, wid = tid >> 6, lane = tid & 63;
  const int ql = lane & 31, hi = lane >> 5;
  const int bh = blockIdx.x >> 4, qblk = blockIdx.x & 15;
  const int qbase = qblk * 128 + wid * 32;
  const u16* Qh = Q + (size_t)bh * SS * HD;
  const u16* Kh = K + (size_t)bh * SS * HD;
  const u16* Vh = Vt + (size_t)bh * HD * SS;

  // Q fragments (B-operand): lane holds Q[qbase+ql][j*16 + hi*8 + 0..7]
  bf16x8 qf[4];
#pragma unroll
  for (int j = 0; j < 4; j++)
    qf[j] = *(const bf16x8*)&Qh[(size_t)(qbase + ql) * HD + j * 16 + hi * 8];

  f32x16 oacc0, oacc1;
#pragma unroll
  for (int r = 0; r < 16; r++) { oacc0[r] = 0.f; oacc1[r] = 0.f; }
  float m2 = -1e30f;   // running max, exp2 domain (scaled)
  float lsum = 0.f;    // running denom

  const float cs = 0.125f * 1.44269504f;  // 1/sqrt(64) * log2(e)

  auto loadT = [&](int kv0, bf16x8* kf, bf16x8* vf) {
#pragma unroll
    for (int j = 0; j < 4; j++)
      kf[j] = *(const bf16x8*)&Kh[(size_t)(kv0 + ql) * HD + j * 16 + hi * 8];
#pragma unroll
    for (int u = 0; u < 4; u++)  // u = dblk*2 + j
      vf[u] = *(const bf16x8*)&Vh[(size_t)((u >> 1) * 32 + ql) * SS + kv0 + (u & 1) * 16 + hi * 8];
  };

  auto tile = [&](const bf16x8* kf, const bf16x8* vf) {
    // S^T tile: rows kv (over regs), cols q (=ql). 4 mfma over K-dim 64.
    f32x16 s;
#pragma unroll
    for (int r = 0; r < 16; r++) s[r] = 0.f;
#pragma unroll
    for (int j = 0; j < 4; j++)
      s = __builtin_amdgcn_mfma_f32_32x32x16_bf16(kf[j], qf[j], s, 0, 0, 0);

    // tile max over this lane's 16 kv, then across the 32-lane-half partner
    float t0 = fmaxf(fmaxf(s[0], s[1]), fmaxf(s[2], s[3]));
    float t1 = fmaxf(fmaxf(s[4], s[5]), fmaxf(s[6], s[7]));
    float t2 = fmaxf(fmaxf(s[8], s[9]), fmaxf(s[10], s[11]));
    float t3 = fmaxf(fmaxf(s[12], s[13]), fmaxf(s[14], s[15]));
    float tmax = cross32_reduce_max(fmaxf(fmaxf(t0, t1), fmaxf(t2, t3))) * cs;

    // defer-max (T13): only rescale when the tile max grew past THR
    if (!__all(tmax - m2 <= 8.f)) {
      float m2n = fmaxf(m2, tmax);
      float al = exp2_(m2 - m2n);
      m2 = m2n;
      lsum *= al;
#pragma unroll
      for (int r = 0; r < 16; r++) { oacc0[r] *= al; oacc1[r] *= al; }
    }

    float p[16];
    float ts = 0.f;
#pragma unroll
    for (int r = 0; r < 16; r++) {
      p[r] = exp2_(fmaf(s[r], cs, -m2));
      ts += p[r];
    }
    lsum += cross32_reduce_sum(ts);

    // build P B-fragments (bf16) via cvt_pk + permlane32_swap (T12)
    u32 w01 = cvt_pk_bf16(p[0], p[1]), w23 = cvt_pk_bf16(p[2], p[3]);
    u32 w45 = cvt_pk_bf16(p[4], p[5]), w67 = cvt_pk_bf16(p[6], p[7]);
    u32 w89 = cvt_pk_bf16(p[8], p[9]), wab = cvt_pk_bf16(p[10], p[11]);
    u32 wcd = cvt_pk_bf16(p[12], p[13]), wef = cvt_pk_bf16(p[14], p[15]);
    lane32_swap(w01, w45);  // -> frag0 word0, word2
    lane32_swap(w23, w67);  // -> frag0 word1, word3
    lane32_swap(w89, wcd);  // -> frag1 word0, word2
    lane32_swap(wab, wef);  // -> frag1 word1, word3
    union { u32 w[4]; bf16x8 v; } f0, f1;
    f0.w[0] = w01; f0.w[1] = w23; f0.w[2] = w45; f0.w[3] = w67;
    f1.w[0] = w89; f1.w[1] = wab; f1.w[2] = wcd; f1.w[3] = wef;

    // O^T += V^T * P  (rows d over regs, col q lane-local)
    oacc0 = __builtin_amdgcn_mfma_f32_32x32x16_bf16(vf[0], f0.v, oacc0, 0, 0, 0);
    oacc0 = __builtin_amdgcn_mfma_f32_32x32x16_bf16(vf[1], f1.v, oacc0, 0, 0, 0);
    oacc1 = __builtin_amdgcn_mfma_f32_32x32x16_bf16(vf[2], f0.v, oacc1, 0, 0, 0);
    oacc1 = __builtin_amdgcn_mfma_f32_32x32x16_bf16(vf[3], f1.v, oacc1, 0, 0, 0);
  };

  bf16x8 kA[4], vA[4], kB[4], vB[4];
  loadT(0, kA, vA);
  for (int kv0 = 0; kv0 < SS; kv0 += 64) {
    loadT(kv0 + 32, kB, vB);
    tile(kA, vA);
    if (kv0 + 64 < SS) loadT(kv0 + 64, kA, vA);
    tile(kB, vB);
  }

  const int b = bh >> 4, h = bh & 15;
  const float inv = 1.0f / lsum;
  u16* Orow = O + (size_t)(b * SS + qbase + ql) * DM + h * HD;
  auto storeAcc = [&](const f32x16& a, int dbase) {
#pragma unroll
    for (int t = 0; t < 4; t++) {
      u64 pk = (u64)f2bf(a[4 * t] * inv) | ((u64)f2bf(a[4 * t + 1] * inv) << 16) |
               ((u64)f2bf(a[4 * t + 2] * inv) << 32) |
               ((u64)f2bf(a[4 * t + 3] * inv) << 48);
      *(u64*)&Orow[dbase + 4 * hi + 8 * t] = pk;
    }
  };
  storeAcc(oacc0, 0);
  storeAcc(oacc1, 32);
}

// ---------------- fused residual + layernorm ----------------
template <bool WB>
__global__ __launch_bounds__(256) void k_res_ln(const float* __restrict__ X,
                                                const float* __restrict__ Y,
                                                const float* __restrict__ gw,
                                                const float* __restrict__ bw,
                                                float* __restrict__ outf,
                                                u16* __restrict__ outb) {
  const int row = blockIdx.x, t = threadIdx.x;
  const float4 xv = ((const float4*)(X + (size_t)row * DM))[t];
  const float4 yv = ((const float4*)(Y + (size_t)row * DM))[t];
  float v0 = xv.x + yv.x, v1 = xv.y + yv.y, v2 = xv.z + yv.z, v3 = xv.w + yv.w;
  float s = v0 + v1 + v2 + v3;
  float s2 = v0 * v0 + v1 * v1 + v2 * v2 + v3 * v3;
#pragma unroll
  for (int off = 32; off >= 1; off >>= 1) {
    s += __shfl_down(s, off);
    s2 += __shfl_down(s2, off);
  }
  __shared__ float ps[4], ps2[4];
  const int wid = t >> 6, lane = t & 63;
  if (lane == 0) { ps[wid] = s; ps2[wid] = s2; }
  __syncthreads();
  const float ts = ps[0] + ps[1] + ps[2] + ps[3];
  const float ts2 = ps2[0] + ps2[1] + ps2[2] + ps2[3];
  const float mu = ts * (1.f / 1024.f);
  const float rs = rsqrtf(ts2 * (1.f / 1024.f) - mu * mu + 1e-5f);
  const float4 g4 = ((const float4*)gw)[t];
  const float4 b4 = ((const float4*)bw)[t];
  float o0 = (v0 - mu) * rs * g4.x + b4.x;
  float o1 = (v1 - mu) * rs * g4.y + b4.y;
  float o2 = (v2 - mu) * rs * g4.z + b4.z;
  float o3 = (v3 - mu) * rs * g4.w + b4.w;
  ((float4*)(outf + (size_t)row * DM))[t] = make_float4(o0, o1, o2, o3);
  if constexpr (WB) {
    u64 pk = (u64)f2bf(o0) | ((u64)f2bf(o1) << 16) | ((u64)f2bf(o2) << 32) |
             ((u64)f2bf(o3) << 48);
    ((u64*)(outb + (size_t)row * DM))[t] = pk;
  }
}

extern "C" void kernel_launch(void* const* d_in, const int* in_sizes, int n_in,
                              void* d_out, int out_size, void* d_ws, size_t ws_size,
                              hipStream_t stream) {
  const float* x = (const float*)d_in[0];
  const float* Wq = (const float*)d_in[1];
  const float* bq = (const float*)d_in[2];
  const float* Wk = (const float*)d_in[3];
  const float* bk = (const float*)d_in[4];
  const float* Wv = (const float*)d_in[5];
  const float* bv = (const float*)d_in[6];
  const float* Wo = (const float*)d_in[7];
  const float* bo = (const float*)d_in[8];
  const float* g1 = (const float*)d_in[9];
  const float* b1 = (const float*)d_in[10];
  const float* g2 = (const float*)d_in[11];
  const float* b2 = (const float*)d_in[12];
  const float* W1 = (const float*)d_in[13];
  const float* bf1 = (const float*)d_in[14];
  const float* W2 = (const float*)d_in[15];
  const float* bf2 = (const float*)d_in[16];
  float* out = (float*)d_out;

  const size_t MB = (size_t)1 << 20;
  if (ws_size < 104 * MB) return;  // workspace layout needs 104 MB
  char* ws = (char*)d_ws;
  u16* WqT = (u16*)(ws + 0 * MB);
  u16* WkT = (u16*)(ws + 2 * MB);
  u16* WvT = (u16*)(ws + 4 * MB);
  u16* WoT = (u16*)(ws + 6 * MB);
  u16* W1T = (u16*)(ws + 8 * MB);   // [4096][1024]
  u16* W2T = (u16*)(ws + 16 * MB);  // [1024][4096]
  u16* xb = (u16*)(ws + 24 * MB);   // [T][D] bf16
  u16* Qb = (u16*)(ws + 32 * MB);   // [B,H,S,hd]
  u16* Kb = (u16*)(ws + 40 * MB);
  u16* Vt = (u16*)(ws + 48 * MB);   // [B,H,hd,S]
  u16* Ob = (u16*)(ws + 24 * MB);   // reuse xb (dead after QKV GEMMs)
  float* attn = (float*)(ws + 64 * MB);  // [T][D] f32
  float* hf = (float*)(ws + 32 * MB);    // reuse Q,K (dead after attn)
  u16* hb = (u16*)(ws + 48 * MB);        // reuse Vt
  u16* f1 = (u16*)(ws + 56 * MB);        // [T][DFF] bf16, 32MB
  float* ffn = (float*)(ws + 88 * MB);   // [T][D] f32

  k_cast<<<4096, 256, 0, stream>>>(x, xb, TT * DM / 4);
  k_transpose_cast<<<dim3(32, 32), 256, 0, stream>>>(Wq, WqT, DM, DM);
  k_transpose_cast<<<dim3(32, 32), 256, 0, stream>>>(Wk, WkT, DM, DM);
  k_transpose_cast<<<dim3(32, 32), 256, 0, stream>>>(Wv, WvT, DM, DM);
  k_transpose_cast<<<dim3(32, 32), 256, 0, stream>>>(Wo, WoT, DM, DM);
  k_transpose_cast<<<dim3(128, 32), 256, 0, stream>>>(W1, W1T, DM, DFF);
  k_transpose_cast<<<dim3(32, 128), 256, 0, stream>>>(W2, W2T, DFF, DM);

  k_gemm<EPI_QKV><<<dim3(8, 32), 256, 0, stream>>>(xb, WqT, bq, Qb, TT, DM, DM);
  k_gemm<EPI_QKV><<<dim3(8, 32), 256, 0, stream>>>(xb, WkT, bk, Kb, TT, DM, DM);
  k_gemm<EPI_VT><<<dim3(8, 32), 256, 0, stream>>>(xb, WvT, bv, Vt, TT, DM, DM);

  k_attn<<<512, 256, 0, stream>>>(Qb, Kb, Vt, Ob);

  k_gemm<EPI_F32><<<dim3(8, 32), 256, 0, stream>>>(Ob, WoT, bo, attn, TT, DM, DM);
  k_res_ln<true><<<4096, 256, 0, stream>>>(x, attn, g1, b1, hf, hb);
  k_gemm<EPI_GELU><<<dim3(32, 32), 256, 0, stream>>>(hb, W1T, bf1, f1, TT, DFF, DM);
  k_gemm<EPI_F32><<<dim3(8, 32), 256, 0, stream>>>(f1, W2T, bf2, ffn, TT, DM, DFF);
  k_res_ln<false><<<4096, 256, 0, stream>>>(hf, ffn, g2, b2, out, nullptr);
}

// Round 3
// 371.383 us; speedup vs baseline: 1.4822x; 1.1857x over previous
//
#include <hip/hip_runtime.h>
#include <cstdint>
#include <cmath>

typedef unsigned short u16;
typedef unsigned int u32;
typedef unsigned long long u64;
typedef __bf16 bf16x8 __attribute__((ext_vector_type(8)));
typedef float f32x4 __attribute__((ext_vector_type(4)));
typedef float f32x16 __attribute__((ext_vector_type(16)));
typedef int v2i __attribute__((ext_vector_type(2)));

#define AS1 __attribute__((address_space(1)))
#define AS3 __attribute__((address_space(3)))

static constexpr int DM = 1024, DFF = 4096, SS = 2048, HH = 16, HD = 64, TT = 4096;
static constexpr size_t MiB = (size_t)1 << 20;
// workspace offsets (bytes)
static constexpr size_t OFF_WQKVT = 0;         // [3072][1024] bf16, 6 MiB
static constexpr size_t OFF_WOT = 6 * MiB;     // [1024][1024] bf16, 2 MiB
static constexpr size_t OFF_W1T = 8 * MiB;     // [4096][1024] bf16, 8 MiB
static constexpr size_t OFF_W2T = 16 * MiB;    // [1024][4096] bf16, 8 MiB
static constexpr size_t OFF_XB = 24 * MiB;     // [4096][1024] bf16, 8 MiB (reused: Ob)
static constexpr size_t OFF_QB = 32 * MiB;     // [B,H,S,hd] bf16, 8 MiB (reused: hf lo)
static constexpr size_t OFF_KB = 40 * MiB;     // 8 MiB (reused: hf hi)
static constexpr size_t OFF_VT = 48 * MiB;     // [B,H,hd,S] bf16, 8 MiB (reused: hb)
static constexpr size_t OFF_FFN1P = 48 * MiB;  // ffn split1 f32, 16 MiB (48-64)
static constexpr size_t OFF_OPART = 64 * MiB;  // [2][32][2048][64] f32, 32 MiB (reused: attn0/attn1, f1)
static constexpr size_t OFF_ATTN1 = 80 * MiB;
static constexpr size_t OFF_ML = 96 * MiB;     // [2][32*2048] float2, 2 MiB
static constexpr size_t OFF_BQKV = 98 * MiB;   // 3072 f32
static constexpr size_t OFF_FFN0P = 0;         // ffn split0 f32, 16 MiB (weights dead)

__device__ __forceinline__ u16 f2bf(float f) {
  union { float f; unsigned u; } c; c.f = f;
  unsigned r = c.u + 0x7fffu + ((c.u >> 16) & 1u);
  return (u16)(r >> 16);
}

__device__ __forceinline__ void gload_lds16(const void* g, void* l) {
  __builtin_amdgcn_global_load_lds((AS1 void*)g, (AS3 void*)l, 16, 0, 0);
}

__device__ __forceinline__ float exp2_(float x) {
#if __has_builtin(__builtin_amdgcn_exp2f)
  return __builtin_amdgcn_exp2f(x);
#else
  return exp2f(x);
#endif
}

__device__ __forceinline__ u32 cvt_pk_bf16(float lo, float hi) {
  u32 r;
  asm("v_cvt_pk_bf16_f32 %0, %1, %2" : "=v"(r) : "v"(lo), "v"(hi));
  return r;
}

__device__ __forceinline__ void lane32_swap(u32& a, u32& b) {
#if __has_builtin(__builtin_amdgcn_permlane32_swap)
  v2i r = __builtin_amdgcn_permlane32_swap((int)a, (int)b, false, false);
  a = (u32)r.x;
  b = (u32)r.y;
#else
  u32 ta = (u32)__shfl_xor((int)a, 32);
  u32 tb = (u32)__shfl_xor((int)b, 32);
  bool hi = (threadIdx.x & 32) != 0;
  u32 na = hi ? tb : a;
  u32 nb = hi ? b : ta;
  a = na;
  b = nb;
#endif
}

__device__ __forceinline__ float cross32_reduce_max(float x) {
  u32 a = __float_as_uint(x), b = a;
  lane32_swap(a, b);
  return fmaxf(__uint_as_float(a), __uint_as_float(b));
}

__device__ __forceinline__ float cross32_reduce_sum(float x) {
  u32 a = __float_as_uint(x), b = a;
  lane32_swap(a, b);
  return __uint_as_float(a) + __uint_as_float(b);
}

// ---------------- cast fp32 -> bf16 ----------------
__global__ __launch_bounds__(256) void k_cast(const float* __restrict__ in,
                                              u16* __restrict__ out, int n4) {
  int i = blockIdx.x * 256 + threadIdx.x;
  if (i < n4) {
    float4 v = ((const float4*)in)[i];
    u64 pk = (u64)f2bf(v.x) | ((u64)f2bf(v.y) << 16) |
             ((u64)f2bf(v.z) << 32) | ((u64)f2bf(v.w) << 48);
    ((u64*)out)[i] = pk;
  }
}

// ------------- transpose+cast: in fp32 [R][C] -> out bf16 [C][R] -------------
__global__ __launch_bounds__(256) void k_transpose_cast(const float* __restrict__ in,
                                                        u16* __restrict__ out,
                                                        int R, int C) {
  __shared__ u16 tile[32][33];
  const int cb = blockIdx.x * 32, rb = blockIdx.y * 32;
  const int tx = threadIdx.x & 31;
  const int ty = threadIdx.x >> 5;
#pragma unroll
  for (int i = 0; i < 4; i++) {
    int r = ty + i * 8;
    tile[r][tx] = f2bf(in[(size_t)(rb + r) * C + cb + tx]);
  }
  __syncthreads();
#pragma unroll
  for (int i = 0; i < 4; i++) {
    int r2 = ty + i * 8;
    out[(size_t)(cb + r2) * R + rb + tx] = tile[tx][r2];
  }
}

// ---------------- concat 3 bias vectors ----------------
__global__ __launch_bounds__(256) void k_concat3(const float* __restrict__ a,
                                                 const float* __restrict__ b,
                                                 const float* __restrict__ c,
                                                 float* __restrict__ out) {
  int i = blockIdx.x * 256 + threadIdx.x;
  if (i < 3072) out[i] = i < 1024 ? a[i] : (i < 2048 ? b[i - 1024] : c[i - 2048]);
}

// ---------------- bf16 MFMA GEMM: C = A[M,Ksub@stride] * Bt[N,Ksub@stride]^T ----------------
// grid.z = split-K index; EPI_F32 partial z writes to Cout + z*zoff, bias only z==0.
enum { EPI_F32 = 0, EPI_GELU = 1, EPI_QKV3 = 2 };

template <int EPI>
__global__ __launch_bounds__(256) void k_gemm(const u16* __restrict__ A,
                                              const u16* __restrict__ Bt,
                                              const float* __restrict__ bias,
                                              void* __restrict__ Cout,
                                              int M, int N, int Ksub, int stride,
                                              size_t zoff) {
  __shared__ __align__(16) u16 Alds[128 * 32];
  __shared__ __align__(16) u16 Blds[128 * 32];
  const int tid = threadIdx.x;
  const int wid = tid >> 6, lane = tid & 63;
  const int lrow = lane & 15, lgrp = lane >> 4;
  const int mrow = blockIdx.y * 128, ncol = blockIdx.x * 128;
  const int z = blockIdx.z;
  const int wr = wid >> 1, wc = wid & 1;

  f32x4 acc[4][4];
#pragma unroll
  for (int m = 0; m < 4; m++)
#pragma unroll
    for (int n = 0; n < 4; n++) acc[m][n] = (f32x4){0.f, 0.f, 0.f, 0.f};

  const int r0 = tid >> 2;
  const int c0 = (tid & 3) * 8;
  const u16* aBase = A + (size_t)(mrow + r0) * stride + (size_t)z * Ksub + c0;
  const u16* bBase = Bt + (size_t)(ncol + r0) * stride + (size_t)z * Ksub + c0;
  char* la = (char*)Alds + wid * 1024;
  char* lb = (char*)Blds + wid * 1024;

  for (int k0 = 0; k0 < Ksub; k0 += 32) {
    gload_lds16(aBase + k0, la);
    gload_lds16(aBase + (size_t)64 * stride + k0, la + 4096);
    gload_lds16(bBase + k0, lb);
    gload_lds16(bBase + (size_t)64 * stride + k0, lb + 4096);
    __syncthreads();
    bf16x8 af[4], bfr[4];
#pragma unroll
    for (int m = 0; m < 4; m++)
      af[m] = *(const bf16x8*)&Alds[(wr * 64 + m * 16 + lrow) * 32 + lgrp * 8];
#pragma unroll
    for (int n = 0; n < 4; n++)
      bfr[n] = *(const bf16x8*)&Blds[(wc * 64 + n * 16 + lrow) * 32 + lgrp * 8];
#pragma unroll
    for (int m = 0; m < 4; m++)
#pragma unroll
      for (int n = 0; n < 4; n++)
        acc[m][n] = __builtin_amdgcn_mfma_f32_16x16x32_bf16(af[m], bfr[n], acc[m][n], 0, 0, 0);
    __syncthreads();
  }

#pragma unroll
  for (int m = 0; m < 4; m++) {
#pragma unroll
    for (int n = 0; n < 4; n++) {
      const int row0 = mrow + wr * 64 + m * 16 + lgrp * 4;
      const int col = ncol + wc * 64 + n * 16 + lrow;
      f32x4 v = acc[m][n];
      if constexpr (EPI == EPI_F32) {
        const float bv = (z == 0) ? bias[col] : 0.0f;
        float* C = (float*)Cout + (size_t)z * zoff;
#pragma unroll
        for (int r = 0; r < 4; r++) C[(size_t)(row0 + r) * N + col] = v[r] + bv;
      } else if constexpr (EPI == EPI_GELU) {
        const float bv = bias[col];
        u16* C = (u16*)Cout;
#pragma unroll
        for (int r = 0; r < 4; r++) {
          float xg = v[r] + bv;
          float gl = 0.5f * xg * (1.0f + erff(xg * 0.70710678118654752f));
          C[(size_t)(row0 + r) * N + col] = f2bf(gl);
        }
      } else {  // EPI_QKV3: Cout = ws base; col 0-1023->Q, 1024-2047->K, 2048-3071->V^T
        const float bv = bias[col];
        char* wsb = (char*)Cout;
        const int seg = col >> 10, cc = col & 1023;
        const int h = cc >> 6, d = cc & 63;
        if (seg < 2) {
          u16* dst = (u16*)(wsb + (seg == 0 ? OFF_QB : OFF_KB));
#pragma unroll
          for (int r = 0; r < 4; r++) {
            const int row = row0 + r;
            const int b = row >> 11, s = row & 2047;
            dst[((size_t)(b * HH + h) * SS + s) * HD + d] = f2bf(v[r] + bv);
          }
        } else {
          u16* Vt = (u16*)(wsb + OFF_VT);
          const int b = row0 >> 11, s = row0 & 2047;
          u64 pk = (u64)f2bf(v[0] + bv) | ((u64)f2bf(v[1] + bv) << 16) |
                   ((u64)f2bf(v[2] + bv) << 32) | ((u64)f2bf(v[3] + bv) << 48);
          *(u64*)&Vt[((size_t)(b * HH + h) * HD + d) * SS + s] = pk;
        }
      }
    }
  }
}

// ---------------- flash attention, KV-split=2, 32x32 swapped-operand ----------------
// Writes unnormalized O^T partials (f32) + (m,l) per row.
__global__ __launch_bounds__(256) void k_attn_split(const u16* __restrict__ Q,
                                                    const u16* __restrict__ K,
                                                    const u16* __restrict__ Vt,
                                                    float* __restrict__ Opart,
                                                    float* __restrict__ ml) {
  const int tid = threadIdx.x, wid = tid >> 6, lane = tid & 63;
  const int ql = lane & 31, hi = lane >> 5;
  const int bx = blockIdx.x;
  const int split = bx >> 9, bh = (bx >> 4) & 31, qblk = bx & 15;
  const int qbase = qblk * 128 + wid * 32;
  const int kvS = split * 1024, kvE = kvS + 1024;
  const u16* Qh = Q + (size_t)bh * SS * HD;
  const u16* Kh = K + (size_t)bh * SS * HD;
  const u16* Vh = Vt + (size_t)bh * HD * SS;

  bf16x8 qf[4];
#pragma unroll
  for (int j = 0; j < 4; j++)
    qf[j] = *(const bf16x8*)&Qh[(size_t)(qbase + ql) * HD + j * 16 + hi * 8];

  f32x16 oacc0, oacc1;
#pragma unroll
  for (int r = 0; r < 16; r++) { oacc0[r] = 0.f; oacc1[r] = 0.f; }
  float m2 = -1e30f;
  float lsum = 0.f;
  const float cs = 0.125f * 1.44269504f;

  auto loadT = [&](int kv0, bf16x8* kf, bf16x8* vf) {
#pragma unroll
    for (int j = 0; j < 4; j++)
      kf[j] = *(const bf16x8*)&Kh[(size_t)(kv0 + ql) * HD + j * 16 + hi * 8];
#pragma unroll
    for (int u = 0; u < 4; u++)
      vf[u] = *(const bf16x8*)&Vh[(size_t)((u >> 1) * 32 + ql) * SS + kv0 + (u & 1) * 16 + hi * 8];
  };

  auto tile = [&](const bf16x8* kf, const bf16x8* vf) {
    f32x16 s;
#pragma unroll
    for (int r = 0; r < 16; r++) s[r] = 0.f;
#pragma unroll
    for (int j = 0; j < 4; j++)
      s = __builtin_amdgcn_mfma_f32_32x32x16_bf16(kf[j], qf[j], s, 0, 0, 0);

    float t0 = fmaxf(fmaxf(s[0], s[1]), fmaxf(s[2], s[3]));
    float t1 = fmaxf(fmaxf(s[4], s[5]), fmaxf(s[6], s[7]));
    float t2 = fmaxf(fmaxf(s[8], s[9]), fmaxf(s[10], s[11]));
    float t3 = fmaxf(fmaxf(s[12], s[13]), fmaxf(s[14], s[15]));
    float tmax = cross32_reduce_max(fmaxf(fmaxf(t0, t1), fmaxf(t2, t3))) * cs;

    if (!__all(tmax - m2 <= 8.f)) {
      float m2n = fmaxf(m2, tmax);
      float al = exp2_(m2 - m2n);
      m2 = m2n;
      lsum *= al;
#pragma unroll
      for (int r = 0; r < 16; r++) { oacc0[r] *= al; oacc1[r] *= al; }
    }

    float p[16];
    float ts = 0.f;
#pragma unroll
    for (int r = 0; r < 16; r++) {
      p[r] = exp2_(fmaf(s[r], cs, -m2));
      ts += p[r];
    }
    lsum += cross32_reduce_sum(ts);

    u32 w01 = cvt_pk_bf16(p[0], p[1]), w23 = cvt_pk_bf16(p[2], p[3]);
    u32 w45 = cvt_pk_bf16(p[4], p[5]), w67 = cvt_pk_bf16(p[6], p[7]);
    u32 w89 = cvt_pk_bf16(p[8], p[9]), wab = cvt_pk_bf16(p[10], p[11]);
    u32 wcd = cvt_pk_bf16(p[12], p[13]), wef = cvt_pk_bf16(p[14], p[15]);
    lane32_swap(w01, w45);
    lane32_swap(w23, w67);
    lane32_swap(w89, wcd);
    lane32_swap(wab, wef);
    union { u32 w[4]; bf16x8 v; } f0, f1;
    f0.w[0] = w01; f0.w[1] = w23; f0.w[2] = w45; f0.w[3] = w67;
    f1.w[0] = w89; f1.w[1] = wab; f1.w[2] = wcd; f1.w[3] = wef;

    oacc0 = __builtin_amdgcn_mfma_f32_32x32x16_bf16(vf[0], f0.v, oacc0, 0, 0, 0);
    oacc0 = __builtin_amdgcn_mfma_f32_32x32x16_bf16(vf[1], f1.v, oacc0, 0, 0, 0);
    oacc1 = __builtin_amdgcn_mfma_f32_32x32x16_bf16(vf[2], f0.v, oacc1, 0, 0, 0);
    oacc1 = __builtin_amdgcn_mfma_f32_32x32x16_bf16(vf[3], f1.v, oacc1, 0, 0, 0);
  };

  bf16x8 kA[4], vA[4], kB[4], vB[4];
  loadT(kvS, kA, vA);
  for (int kv0 = kvS; kv0 < kvE; kv0 += 64) {
    loadT(kv0 + 32, kB, vB);
    tile(kA, vA);
    if (kv0 + 64 < kvE) loadT(kv0 + 64, kA, vA);
    tile(kB, vB);
  }

  const int rowidx = bh * SS + qbase + ql;
  float* Orow = Opart + ((size_t)split * 32 * SS + rowidx) * HD;
  auto storeAcc = [&](const f32x16& a, int dbase) {
#pragma unroll
    for (int t = 0; t < 4; t++)
      *(float4*)&Orow[dbase + 4 * hi + 8 * t] =
          make_float4(a[4 * t], a[4 * t + 1], a[4 * t + 2], a[4 * t + 3]);
  };
  storeAcc(oacc0, 0);
  storeAcc(oacc1, 32);
  if (hi == 0)
    *(float2*)&ml[((size_t)split * 32 * SS + rowidx) * 2] = make_float2(m2, lsum);
}

// ---------------- merge the two KV-split partials -> bf16 O [T][DM] ----------------
__global__ __launch_bounds__(256) void k_attn_merge(const float* __restrict__ Opart,
                                                    const float* __restrict__ ml,
                                                    u16* __restrict__ O) {
  const int g = blockIdx.x * 256 + threadIdx.x;  // 1,048,576 threads
  const int row = g >> 4, dseg = g & 15;
  const float2 m0 = ((const float2*)ml)[row];
  const float2 m1 = ((const float2*)ml)[32 * SS + row];
  const float mm = fmaxf(m0.x, m1.x);
  const float w0 = exp2f(m0.x - mm), w1 = exp2f(m1.x - mm);
  const float inv = 1.0f / (m0.y * w0 + m1.y * w1);
  const float4 o0 = ((const float4*)Opart)[(size_t)row * 16 + dseg];
  const float4 o1 = ((const float4*)Opart)[(size_t)(32 * SS + row) * 16 + dseg];
  const float a = (o0.x * w0 + o1.x * w1) * inv;
  const float b = (o0.y * w0 + o1.y * w1) * inv;
  const float c = (o0.z * w0 + o1.z * w1) * inv;
  const float d = (o0.w * w0 + o1.w * w1) * inv;
  const int bh = row >> 11, s = row & 2047;
  const int bb = bh >> 4, h = bh & 15;
  u64 pk = (u64)f2bf(a) | ((u64)f2bf(b) << 16) | ((u64)f2bf(c) << 32) | ((u64)f2bf(d) << 48);
  *(u64*)&O[((size_t)(bb * SS + s) * DM) + h * HD + dseg * 4] = pk;
}

// ---------------- fused residual(2-way) + layernorm ----------------
template <bool WB>
__global__ __launch_bounds__(256) void k_res_ln(const float* __restrict__ X,
                                                const float* __restrict__ Y0,
                                                const float* __restrict__ Y1,
                                                const float* __restrict__ gw,
                                                const float* __restrict__ bw,
                                                float* __restrict__ outf,
                                                u16* __restrict__ outb) {
  const int row = blockIdx.x, t = threadIdx.x;
  const float4 xv = ((const float4*)(X + (size_t)row * DM))[t];
  const float4 y0 = ((const float4*)(Y0 + (size_t)row * DM))[t];
  const float4 y1 = ((const float4*)(Y1 + (size_t)row * DM))[t];
  float v0 = xv.x + y0.x + y1.x, v1 = xv.y + y0.y + y1.y;
  float v2 = xv.z + y0.z + y1.z, v3 = xv.w + y0.w + y1.w;
  float s = v0 + v1 + v2 + v3;
  float s2 = v0 * v0 + v1 * v1 + v2 * v2 + v3 * v3;
#pragma unroll
  for (int off = 32; off >= 1; off >>= 1) {
    s += __shfl_down(s, off);
    s2 += __shfl_down(s2, off);
  }
  __shared__ float ps[4], ps2[4];
  const int wid = t >> 6, lane = t & 63;
  if (lane == 0) { ps[wid] = s; ps2[wid] = s2; }
  __syncthreads();
  const float ts = ps[0] + ps[1] + ps[2] + ps[3];
  const float ts2 = ps2[0] + ps2[1] + ps2[2] + ps2[3];
  const float mu = ts * (1.f / 1024.f);
  const float rs = rsqrtf(ts2 * (1.f / 1024.f) - mu * mu + 1e-5f);
  const float4 g4 = ((const float4*)gw)[t];
  const float4 b4 = ((const float4*)bw)[t];
  float o0 = (v0 - mu) * rs * g4.x + b4.x;
  float o1 = (v1 - mu) * rs * g4.y + b4.y;
  float o2 = (v2 - mu) * rs * g4.z + b4.z;
  float o3 = (v3 - mu) * rs * g4.w + b4.w;
  ((float4*)(outf + (size_t)row * DM))[t] = make_float4(o0, o1, o2, o3);
  if constexpr (WB) {
    u64 pk = (u64)f2bf(o0) | ((u64)f2bf(o1) << 16) | ((u64)f2bf(o2) << 32) |
             ((u64)f2bf(o3) << 48);
    ((u64*)(outb + (size_t)row * DM))[t] = pk;
  }
}

extern "C" void kernel_launch(void* const* d_in, const int* in_sizes, int n_in,
                              void* d_out, int out_size, void* d_ws, size_t ws_size,
                              hipStream_t stream) {
  const float* x = (const float*)d_in[0];
  const float* Wq = (const float*)d_in[1];
  const float* bq = (const float*)d_in[2];
  const float* Wk = (const float*)d_in[3];
  const float* bk = (const float*)d_in[4];
  const float* Wv = (const float*)d_in[5];
  const float* bv = (const float*)d_in[6];
  const float* Wo = (const float*)d_in[7];
  const float* bo = (const float*)d_in[8];
  const float* g1 = (const float*)d_in[9];
  const float* b1 = (const float*)d_in[10];
  const float* g2 = (const float*)d_in[11];
  const float* b2 = (const float*)d_in[12];
  const float* W1 = (const float*)d_in[13];
  const float* bf1 = (const float*)d_in[14];
  const float* W2 = (const float*)d_in[15];
  const float* bf2 = (const float*)d_in[16];
  float* out = (float*)d_out;

  if (ws_size < 99 * MiB) return;
  char* ws = (char*)d_ws;
  u16* WqkvT = (u16*)(ws + OFF_WQKVT);
  u16* WoT = (u16*)(ws + OFF_WOT);
  u16* W1T = (u16*)(ws + OFF_W1T);
  u16* W2T = (u16*)(ws + OFF_W2T);
  u16* xb = (u16*)(ws + OFF_XB);
  u16* Qb = (u16*)(ws + OFF_QB);
  u16* Kb = (u16*)(ws + OFF_KB);
  u16* Vt = (u16*)(ws + OFF_VT);
  u16* Ob = (u16*)(ws + OFF_XB);          // reuse xb after QKV
  float* Opart = (float*)(ws + OFF_OPART);
  float* ml = (float*)(ws + OFF_ML);
  float* bqkv = (float*)(ws + OFF_BQKV);
  float* attn0 = (float*)(ws + OFF_OPART);  // reuse Opart after merge
  float* attn1 = (float*)(ws + OFF_ATTN1);
  float* hf = (float*)(ws + OFF_QB);        // 32-48 MiB
  u16* hb = (u16*)(ws + OFF_VT);            // 48-56 MiB
  u16* f1 = (u16*)(ws + OFF_OPART);         // 64-96 MiB (attn partials dead)
  float* ffn0 = (float*)(ws + OFF_FFN0P);   // 0-16 MiB (weights dead)
  float* ffn1 = (float*)(ws + OFF_FFN1P);   // 48-64 MiB (hb dead)

  k_cast<<<4096, 256, 0, stream>>>(x, xb, TT * DM / 4);
  k_transpose_cast<<<dim3(32, 32), 256, 0, stream>>>(Wq, WqkvT, DM, DM);
  k_transpose_cast<<<dim3(32, 32), 256, 0, stream>>>(Wk, WqkvT + 1024 * 1024, DM, DM);
  k_transpose_cast<<<dim3(32, 32), 256, 0, stream>>>(Wv, WqkvT + 2048 * 1024, DM, DM);
  k_transpose_cast<<<dim3(32, 32), 256, 0, stream>>>(Wo, WoT, DM, DM);
  k_transpose_cast<<<dim3(128, 32), 256, 0, stream>>>(W1, W1T, DM, DFF);
  k_transpose_cast<<<dim3(32, 128), 256, 0, stream>>>(W2, W2T, DFF, DM);
  k_concat3<<<12, 256, 0, stream>>>(bq, bk, bv, bqkv);

  // fused QKV projection: [4096,1024] x [3072,1024]^T, epilogue scatters Q/K/V^T
  k_gemm<EPI_QKV3><<<dim3(24, 32, 1), 256, 0, stream>>>(xb, WqkvT, bqkv, ws, TT, 3072,
                                                        DM, DM, 0);

  k_attn_split<<<1024, 256, 0, stream>>>(Qb, Kb, Vt, Opart, ml);
  k_attn_merge<<<4096, 256, 0, stream>>>(Opart, ml, Ob);

  // Wo projection, split-K=2 into attn0/attn1
  k_gemm<EPI_F32><<<dim3(8, 32, 2), 256, 0, stream>>>(Ob, WoT, bo, attn0, TT, DM,
                                                      DM / 2, DM,
                                                      (size_t)TT * DM);
  k_res_ln<true><<<4096, 256, 0, stream>>>(x, attn0, attn1, g1, b1, hf, hb);

  k_gemm<EPI_GELU><<<dim3(32, 32, 1), 256, 0, stream>>>(hb, W1T, bf1, f1, TT, DFF,
                                                        DM, DM, 0);
  // FFN2, split-K=2: partial0 -> ws+0, partial1 -> ws+48MiB
  k_gemm<EPI_F32><<<dim3(8, 32, 2), 256, 0, stream>>>(f1, W2T, bf2, ffn0, TT, DM,
                                                      DFF / 2, DFF,
                                                      OFF_FFN1P / 4);
  k_res_ln<false><<<4096, 256, 0, stream>>>(hf, ffn0, ffn1, g2, b2, out, nullptr);
}

// Round 4
// 309.451 us; speedup vs baseline: 1.7788x; 1.2001x over previous
//
#include <hip/hip_runtime.h>
#include <cstdint>
#include <cmath>

typedef unsigned short u16;
typedef unsigned int u32;
typedef unsigned long long u64;
typedef __bf16 bf16x8 __attribute__((ext_vector_type(8)));
typedef float f32x4 __attribute__((ext_vector_type(4)));
typedef float f32x16 __attribute__((ext_vector_type(16)));
typedef int v2i __attribute__((ext_vector_type(2)));

#define AS1 __attribute__((address_space(1)))
#define AS3 __attribute__((address_space(3)))

static constexpr int DM = 1024, DFF = 4096, SS = 2048, HH = 16, HD = 64, TT = 4096;
static constexpr size_t MiB = (size_t)1 << 20;
// workspace offsets (bytes)
static constexpr size_t OFF_WQKVT = 0;         // [3072][1024] bf16, 6 MiB
static constexpr size_t OFF_WOT = 6 * MiB;     // [1024][1024] bf16, 2 MiB
static constexpr size_t OFF_W1T = 8 * MiB;     // [4096][1024] bf16, 8 MiB
static constexpr size_t OFF_W2T = 16 * MiB;    // [1024][4096] bf16, 8 MiB
static constexpr size_t OFF_XB = 24 * MiB;     // [4096][1024] bf16, 8 MiB (reused: Ob)
static constexpr size_t OFF_QB = 32 * MiB;     // [B,H,S,hd] bf16, 8 MiB (reused: hf lo)
static constexpr size_t OFF_KB = 40 * MiB;     // 8 MiB (reused: hf hi)
static constexpr size_t OFF_VT = 48 * MiB;     // blocked V^T, 8 MiB (reused: hb)
static constexpr size_t OFF_FFN1P = 48 * MiB;  // ffn split1 f32, 16 MiB (48-64)
static constexpr size_t OFF_OPART = 64 * MiB;  // [2][32][2048][64] f32, 32 MiB
static constexpr size_t OFF_ATTN1 = 80 * MiB;
static constexpr size_t OFF_ML = 96 * MiB;     // [2][32*2048] float2, 2 MiB
static constexpr size_t OFF_BQKV = 98 * MiB;   // 3072 f32
static constexpr size_t OFF_FFN0P = 0;         // ffn split0 f32, 16 MiB (weights dead)

__device__ __forceinline__ u16 f2bf(float f) {
  union { float f; unsigned u; } c; c.f = f;
  unsigned r = c.u + 0x7fffu + ((c.u >> 16) & 1u);
  return (u16)(r >> 16);
}

__device__ __forceinline__ void gload_lds16(const void* g, void* l) {
  __builtin_amdgcn_global_load_lds((AS1 void*)g, (AS3 void*)l, 16, 0, 0);
}

__device__ __forceinline__ float exp2_(float x) {
#if __has_builtin(__builtin_amdgcn_exp2f)
  return __builtin_amdgcn_exp2f(x);
#else
  return exp2f(x);
#endif
}

__device__ __forceinline__ u32 cvt_pk_bf16(float lo, float hi) {
  u32 r;
  asm("v_cvt_pk_bf16_f32 %0, %1, %2" : "=v"(r) : "v"(lo), "v"(hi));
  return r;
}

__device__ __forceinline__ void lane32_swap(u32& a, u32& b) {
#if __has_builtin(__builtin_amdgcn_permlane32_swap)
  v2i r = __builtin_amdgcn_permlane32_swap((int)a, (int)b, false, false);
  a = (u32)r.x;
  b = (u32)r.y;
#else
  u32 ta = (u32)__shfl_xor((int)a, 32);
  u32 tb = (u32)__shfl_xor((int)b, 32);
  bool hi = (threadIdx.x & 32) != 0;
  u32 na = hi ? tb : a;
  u32 nb = hi ? b : ta;
  a = na;
  b = nb;
#endif
}

__device__ __forceinline__ float cross32_reduce_max(float x) {
  u32 a = __float_as_uint(x), b = a;
  lane32_swap(a, b);
  return fmaxf(__uint_as_float(a), __uint_as_float(b));
}

__device__ __forceinline__ float cross32_reduce_sum(float x) {
  u32 a = __float_as_uint(x), b = a;
  lane32_swap(a, b);
  return __uint_as_float(a) + __uint_as_float(b);
}

// ---------------- cast fp32 -> bf16 ----------------
__global__ __launch_bounds__(256) void k_cast(const float* __restrict__ in,
                                              u16* __restrict__ out, int n4) {
  int i = blockIdx.x * 256 + threadIdx.x;
  if (i < n4) {
    float4 v = ((const float4*)in)[i];
    u64 pk = (u64)f2bf(v.x) | ((u64)f2bf(v.y) << 16) |
             ((u64)f2bf(v.z) << 32) | ((u64)f2bf(v.w) << 48);
    ((u64*)out)[i] = pk;
  }
}

// ------------- transpose+cast: in fp32 [R][C] -> out bf16 [C][R] -------------
__global__ __launch_bounds__(256) void k_transpose_cast(const float* __restrict__ in,
                                                        u16* __restrict__ out,
                                                        int R, int C) {
  __shared__ u16 tile[32][33];
  const int cb = blockIdx.x * 32, rb = blockIdx.y * 32;
  const int tx = threadIdx.x & 31;
  const int ty = threadIdx.x >> 5;
#pragma unroll
  for (int i = 0; i < 4; i++) {
    int r = ty + i * 8;
    tile[r][tx] = f2bf(in[(size_t)(rb + r) * C + cb + tx]);
  }
  __syncthreads();
#pragma unroll
  for (int i = 0; i < 4; i++) {
    int r2 = ty + i * 8;
    out[(size_t)(cb + r2) * R + rb + tx] = tile[tx][r2];
  }
}

// ---------------- concat 3 bias vectors ----------------
__global__ __launch_bounds__(256) void k_concat3(const float* __restrict__ a,
                                                 const float* __restrict__ b,
                                                 const float* __restrict__ c,
                                                 float* __restrict__ out) {
  int i = blockIdx.x * 256 + threadIdx.x;
  if (i < 3072) out[i] = i < 1024 ? a[i] : (i < 2048 ? b[i - 1024] : c[i - 2048]);
}

// ---------------- bf16 MFMA GEMM: C = A[M,Ksub@stride] * Bt[N,Ksub@stride]^T ----------------
enum { EPI_F32 = 0, EPI_GELU = 1, EPI_QKV3 = 2 };

template <int EPI>
__global__ __launch_bounds__(256) void k_gemm(const u16* __restrict__ A,
                                              const u16* __restrict__ Bt,
                                              const float* __restrict__ bias,
                                              void* __restrict__ Cout,
                                              int M, int N, int Ksub, int stride,
                                              size_t zoff) {
  __shared__ __align__(16) u16 Alds[128 * 32];
  __shared__ __align__(16) u16 Blds[128 * 32];
  const int tid = threadIdx.x;
  const int wid = tid >> 6, lane = tid & 63;
  const int lrow = lane & 15, lgrp = lane >> 4;
  const int mrow = blockIdx.y * 128, ncol = blockIdx.x * 128;
  const int z = blockIdx.z;
  const int wr = wid >> 1, wc = wid & 1;

  f32x4 acc[4][4];
#pragma unroll
  for (int m = 0; m < 4; m++)
#pragma unroll
    for (int n = 0; n < 4; n++) acc[m][n] = (f32x4){0.f, 0.f, 0.f, 0.f};

  const int r0 = tid >> 2;
  const int c0 = (tid & 3) * 8;
  const u16* aBase = A + (size_t)(mrow + r0) * stride + (size_t)z * Ksub + c0;
  const u16* bBase = Bt + (size_t)(ncol + r0) * stride + (size_t)z * Ksub + c0;
  char* la = (char*)Alds + wid * 1024;
  char* lb = (char*)Blds + wid * 1024;

  for (int k0 = 0; k0 < Ksub; k0 += 32) {
    gload_lds16(aBase + k0, la);
    gload_lds16(aBase + (size_t)64 * stride + k0, la + 4096);
    gload_lds16(bBase + k0, lb);
    gload_lds16(bBase + (size_t)64 * stride + k0, lb + 4096);
    __syncthreads();
    bf16x8 af[4], bfr[4];
#pragma unroll
    for (int m = 0; m < 4; m++)
      af[m] = *(const bf16x8*)&Alds[(wr * 64 + m * 16 + lrow) * 32 + lgrp * 8];
#pragma unroll
    for (int n = 0; n < 4; n++)
      bfr[n] = *(const bf16x8*)&Blds[(wc * 64 + n * 16 + lrow) * 32 + lgrp * 8];
#pragma unroll
    for (int m = 0; m < 4; m++)
#pragma unroll
      for (int n = 0; n < 4; n++)
        acc[m][n] = __builtin_amdgcn_mfma_f32_16x16x32_bf16(af[m], bfr[n], acc[m][n], 0, 0, 0);
    __syncthreads();
  }

#pragma unroll
  for (int m = 0; m < 4; m++) {
#pragma unroll
    for (int n = 0; n < 4; n++) {
      const int row0 = mrow + wr * 64 + m * 16 + lgrp * 4;
      const int col = ncol + wc * 64 + n * 16 + lrow;
      f32x4 v = acc[m][n];
      if constexpr (EPI == EPI_F32) {
        const float bv = (z == 0) ? bias[col] : 0.0f;
        float* C = (float*)Cout + (size_t)z * zoff;
#pragma unroll
        for (int r = 0; r < 4; r++) C[(size_t)(row0 + r) * N + col] = v[r] + bv;
      } else if constexpr (EPI == EPI_GELU) {
        const float bv = bias[col];
        u16* C = (u16*)Cout;
#pragma unroll
        for (int r = 0; r < 4; r++) {
          float xg = v[r] + bv;
          float gl = 0.5f * xg * (1.0f + erff(xg * 0.70710678118654752f));
          C[(size_t)(row0 + r) * N + col] = f2bf(gl);
        }
      } else {  // EPI_QKV3
        const float bv = bias[col];
        char* wsb = (char*)Cout;
        const int seg = col >> 10, cc = col & 1023;
        const int h = cc >> 6, d = cc & 63;
        if (seg < 2) {
          u16* dst = (u16*)(wsb + (seg == 0 ? OFF_QB : OFF_KB));
#pragma unroll
          for (int r = 0; r < 4; r++) {
            const int row = row0 + r;
            const int b = row >> 11, s = row & 2047;
            dst[((size_t)(b * HH + h) * SS + s) * HD + d] = f2bf(v[r] + bv);
          }
        } else {
          // V^T blocked: [bh][s>>6][d][s&63], 64x64 bf16 blocks (8KB contiguous)
          u16* Vt = (u16*)(wsb + OFF_VT);
          const int b = row0 >> 11, s = row0 & 2047;
          u64 pk = (u64)f2bf(v[0] + bv) | ((u64)f2bf(v[1] + bv) << 16) |
                   ((u64)f2bf(v[2] + bv) << 32) | ((u64)f2bf(v[3] + bv) << 48);
          size_t addr = ((size_t)(b * HH + h) * (SS / 64) + (s >> 6)) * 4096 +
                        (size_t)d * 64 + (s & 63);
          *(u64*)&Vt[addr] = pk;
        }
      }
    }
  }
}

// ---------------- flash attention, KV-split=2, LDS-staged K/V ----------------
// K: [bh][s][64] bf16; Vt blocked: [bh][s/64][64][64] bf16.
// Per block: 4 waves share double-buffered LDS K/V 64-KV tiles (XOR-swizzled).
__global__ __launch_bounds__(256) void k_attn_split(const u16* __restrict__ Q,
                                                    const u16* __restrict__ K,
                                                    const u16* __restrict__ Vt,
                                                    float* __restrict__ Opart,
                                                    float* __restrict__ ml) {
  __shared__ __align__(16) u16 Kl[2][4096];  // [buf][64 rows x 64 cols]
  __shared__ __align__(16) u16 Vl[2][4096];  // [buf][64 d x 64 s]
  const int tid = threadIdx.x, wid = tid >> 6, lane = tid & 63;
  const int ql = lane & 31, hi = lane >> 5;
  const int bx = blockIdx.x;
  const int split = bx >> 9, bh = (bx >> 4) & 31, qblk = bx & 15;
  const int qbase = qblk * 128 + wid * 32;
  const int kvS = split * 1024;
  const u16* Qh = Q + (size_t)bh * SS * HD;
  const u16* Kh = K + (size_t)bh * SS * HD;
  const u16* Vh = Vt + (size_t)bh * HD * SS;  // blocked layout, same extent

  // per-lane swizzled source offset within a 1KB staging chunk:
  // row-in-chunk = lane>>3 (128B rows), byte = ((lane&7)*16) ^ ((lane>>3 & 7)<<4)
  const int lrow3 = lane >> 3;
  const int lin = lrow3 * 128 + ((((lane & 7) << 4)) ^ (lrow3 << 4));
  const int kswz = (ql & 7) << 4;  // read-side XOR (row&7)<<4

  auto stage = [&](int kv0, int bufi) {
    const char* Ks = (const char*)Kh + (size_t)kv0 * 128 + wid * 2048 + lin;
    const char* Vs = (const char*)Vh + ((size_t)(kv0 >> 6)) * 8192 + wid * 2048 + lin;
    char* kd = (char*)&Kl[bufi][0] + wid * 2048;
    char* vd = (char*)&Vl[bufi][0] + wid * 2048;
    gload_lds16(Ks, kd);
    gload_lds16(Ks + 1024, kd + 1024);
    gload_lds16(Vs, vd);
    gload_lds16(Vs + 1024, vd + 1024);
  };

  bf16x8 qf[4];
#pragma unroll
  for (int j = 0; j < 4; j++)
    qf[j] = *(const bf16x8*)&Qh[(size_t)(qbase + ql) * HD + j * 16 + hi * 8];

  f32x16 oacc0, oacc1;
#pragma unroll
  for (int r = 0; r < 16; r++) { oacc0[r] = 0.f; oacc1[r] = 0.f; }
  float m2 = -1e30f;
  float lsum = 0.f;
  const float cs = 0.125f * 1.44269504f;

  auto tileC = [&](int bufi, int tt) {
    const char* Kb = (const char*)&Kl[bufi][0];
    const char* Vb = (const char*)&Vl[bufi][0];
    bf16x8 kf[4];
#pragma unroll
    for (int j = 0; j < 4; j++)
      kf[j] = *(const bf16x8*)(Kb + (tt * 32 + ql) * 128 + ((j * 32 + hi * 16) ^ kswz));

    f32x16 s;
#pragma unroll
    for (int r = 0; r < 16; r++) s[r] = 0.f;
#pragma unroll
    for (int j = 0; j < 4; j++)
      s = __builtin_amdgcn_mfma_f32_32x32x16_bf16(kf[j], qf[j], s, 0, 0, 0);

    float t0 = fmaxf(fmaxf(s[0], s[1]), fmaxf(s[2], s[3]));
    float t1 = fmaxf(fmaxf(s[4], s[5]), fmaxf(s[6], s[7]));
    float t2 = fmaxf(fmaxf(s[8], s[9]), fmaxf(s[10], s[11]));
    float t3 = fmaxf(fmaxf(s[12], s[13]), fmaxf(s[14], s[15]));
    float tmax = cross32_reduce_max(fmaxf(fmaxf(t0, t1), fmaxf(t2, t3))) * cs;

    if (!__all(tmax - m2 <= 8.f)) {
      float m2n = fmaxf(m2, tmax);
      float al = exp2_(m2 - m2n);
      m2 = m2n;
      lsum *= al;
#pragma unroll
      for (int r = 0; r < 16; r++) { oacc0[r] *= al; oacc1[r] *= al; }
    }

    float p[16];
    float ts = 0.f;
#pragma unroll
    for (int r = 0; r < 16; r++) {
      p[r] = exp2_(fmaf(s[r], cs, -m2));
      ts += p[r];
    }
    lsum += cross32_reduce_sum(ts);

    u32 w01 = cvt_pk_bf16(p[0], p[1]), w23 = cvt_pk_bf16(p[2], p[3]);
    u32 w45 = cvt_pk_bf16(p[4], p[5]), w67 = cvt_pk_bf16(p[6], p[7]);
    u32 w89 = cvt_pk_bf16(p[8], p[9]), wab = cvt_pk_bf16(p[10], p[11]);
    u32 wcd = cvt_pk_bf16(p[12], p[13]), wef = cvt_pk_bf16(p[14], p[15]);
    lane32_swap(w01, w45);
    lane32_swap(w23, w67);
    lane32_swap(w89, wcd);
    lane32_swap(wab, wef);
    union { u32 w[4]; bf16x8 v; } f0, f1;
    f0.w[0] = w01; f0.w[1] = w23; f0.w[2] = w45; f0.w[3] = w67;
    f1.w[0] = w89; f1.w[1] = wab; f1.w[2] = wcd; f1.w[3] = wef;

    bf16x8 vf[4];
#pragma unroll
    for (int u = 0; u < 4; u++)
      vf[u] = *(const bf16x8*)(Vb + ((u >> 1) * 32 + ql) * 128 +
                               ((tt * 64 + (u & 1) * 32 + hi * 16) ^ kswz));

    oacc0 = __builtin_amdgcn_mfma_f32_32x32x16_bf16(vf[0], f0.v, oacc0, 0, 0, 0);
    oacc0 = __builtin_amdgcn_mfma_f32_32x32x16_bf16(vf[1], f1.v, oacc0, 0, 0, 0);
    oacc1 = __builtin_amdgcn_mfma_f32_32x32x16_bf16(vf[2], f0.v, oacc1, 0, 0, 0);
    oacc1 = __builtin_amdgcn_mfma_f32_32x32x16_bf16(vf[3], f1.v, oacc1, 0, 0, 0);
  };

  stage(kvS, 0);
  __syncthreads();
  int cur = 0;
  for (int it = 0; it < 16; ++it) {
    if (it + 1 < 16) stage(kvS + (it + 1) * 64, cur ^ 1);
    tileC(cur, 0);
    tileC(cur, 1);
    __syncthreads();
    cur ^= 1;
  }

  const int rowidx = bh * SS + qbase + ql;
  float* Orow = Opart + ((size_t)split * 32 * SS + rowidx) * HD;
  auto storeAcc = [&](const f32x16& a, int dbase) {
#pragma unroll
    for (int t = 0; t < 4; t++)
      *(float4*)&Orow[dbase + 4 * hi + 8 * t] =
          make_float4(a[4 * t], a[4 * t + 1], a[4 * t + 2], a[4 * t + 3]);
  };
  storeAcc(oacc0, 0);
  storeAcc(oacc1, 32);
  if (hi == 0)
    *(float2*)&ml[((size_t)split * 32 * SS + rowidx) * 2] = make_float2(m2, lsum);
}

// ---------------- merge the two KV-split partials -> bf16 O [T][DM] ----------------
__global__ __launch_bounds__(256) void k_attn_merge(const float* __restrict__ Opart,
                                                    const float* __restrict__ ml,
                                                    u16* __restrict__ O) {
  const int g = blockIdx.x * 256 + threadIdx.x;
  const int row = g >> 4, dseg = g & 15;
  const float2 m0 = ((const float2*)ml)[row];
  const float2 m1 = ((const float2*)ml)[32 * SS + row];
  const float mm = fmaxf(m0.x, m1.x);
  const float w0 = exp2f(m0.x - mm), w1 = exp2f(m1.x - mm);
  const float inv = 1.0f / (m0.y * w0 + m1.y * w1);
  const float4 o0 = ((const float4*)Opart)[(size_t)row * 16 + dseg];
  const float4 o1 = ((const float4*)Opart)[(size_t)(32 * SS + row) * 16 + dseg];
  const float a = (o0.x * w0 + o1.x * w1) * inv;
  const float b = (o0.y * w0 + o1.y * w1) * inv;
  const float c = (o0.z * w0 + o1.z * w1) * inv;
  const float d = (o0.w * w0 + o1.w * w1) * inv;
  const int bh = row >> 11, s = row & 2047;
  const int bb = bh >> 4, h = bh & 15;
  u64 pk = (u64)f2bf(a) | ((u64)f2bf(b) << 16) | ((u64)f2bf(c) << 32) | ((u64)f2bf(d) << 48);
  *(u64*)&O[((size_t)(bb * SS + s) * DM) + h * HD + dseg * 4] = pk;
}

// ---------------- fused residual(2-way) + layernorm ----------------
template <bool WB>
__global__ __launch_bounds__(256) void k_res_ln(const float* __restrict__ X,
                                                const float* __restrict__ Y0,
                                                const float* __restrict__ Y1,
                                                const float* __restrict__ gw,
                                                const float* __restrict__ bw,
                                                float* __restrict__ outf,
                                                u16* __restrict__ outb) {
  const int row = blockIdx.x, t = threadIdx.x;
  const float4 xv = ((const float4*)(X + (size_t)row * DM))[t];
  const float4 y0 = ((const float4*)(Y0 + (size_t)row * DM))[t];
  const float4 y1 = ((const float4*)(Y1 + (size_t)row * DM))[t];
  float v0 = xv.x + y0.x + y1.x, v1 = xv.y + y0.y + y1.y;
  float v2 = xv.z + y0.z + y1.z, v3 = xv.w + y0.w + y1.w;
  float s = v0 + v1 + v2 + v3;
  float s2 = v0 * v0 + v1 * v1 + v2 * v2 + v3 * v3;
#pragma unroll
  for (int off = 32; off >= 1; off >>= 1) {
    s += __shfl_down(s, off);
    s2 += __shfl_down(s2, off);
  }
  __shared__ float ps[4], ps2[4];
  const int wid = t >> 6, lane = t & 63;
  if (lane == 0) { ps[wid] = s; ps2[wid] = s2; }
  __syncthreads();
  const float ts = ps[0] + ps[1] + ps[2] + ps[3];
  const float ts2 = ps2[0] + ps2[1] + ps2[2] + ps2[3];
  const float mu = ts * (1.f / 1024.f);
  const float rs = rsqrtf(ts2 * (1.f / 1024.f) - mu * mu + 1e-5f);
  const float4 g4 = ((const float4*)gw)[t];
  const float4 b4 = ((const float4*)bw)[t];
  float o0 = (v0 - mu) * rs * g4.x + b4.x;
  float o1 = (v1 - mu) * rs * g4.y + b4.y;
  float o2 = (v2 - mu) * rs * g4.z + b4.z;
  float o3 = (v3 - mu) * rs * g4.w + b4.w;
  ((float4*)(outf + (size_t)row * DM))[t] = make_float4(o0, o1, o2, o3);
  if constexpr (WB) {
    u64 pk = (u64)f2bf(o0) | ((u64)f2bf(o1) << 16) | ((u64)f2bf(o2) << 32) |
             ((u64)f2bf(o3) << 48);
    ((u64*)(outb + (size_t)row * DM))[t] = pk;
  }
}

extern "C" void kernel_launch(void* const* d_in, const int* in_sizes, int n_in,
                              void* d_out, int out_size, void* d_ws, size_t ws_size,
                              hipStream_t stream) {
  const float* x = (const float*)d_in[0];
  const float* Wq = (const float*)d_in[1];
  const float* bq = (const float*)d_in[2];
  const float* Wk = (const float*)d_in[3];
  const float* bk = (const float*)d_in[4];
  const float* Wv = (const float*)d_in[5];
  const float* bv = (const float*)d_in[6];
  const float* Wo = (const float*)d_in[7];
  const float* bo = (const float*)d_in[8];
  const float* g1 = (const float*)d_in[9];
  const float* b1 = (const float*)d_in[10];
  const float* g2 = (const float*)d_in[11];
  const float* b2 = (const float*)d_in[12];
  const float* W1 = (const float*)d_in[13];
  const float* bf1 = (const float*)d_in[14];
  const float* W2 = (const float*)d_in[15];
  const float* bf2 = (const float*)d_in[16];
  float* out = (float*)d_out;

  if (ws_size < 99 * MiB) return;
  char* ws = (char*)d_ws;
  u16* WqkvT = (u16*)(ws + OFF_WQKVT);
  u16* WoT = (u16*)(ws + OFF_WOT);
  u16* W1T = (u16*)(ws + OFF_W1T);
  u16* W2T = (u16*)(ws + OFF_W2T);
  u16* xb = (u16*)(ws + OFF_XB);
  u16* Qb = (u16*)(ws + OFF_QB);
  u16* Kb = (u16*)(ws + OFF_KB);
  u16* Vt = (u16*)(ws + OFF_VT);
  u16* Ob = (u16*)(ws + OFF_XB);
  float* Opart = (float*)(ws + OFF_OPART);
  float* ml = (float*)(ws + OFF_ML);
  float* bqkv = (float*)(ws + OFF_BQKV);
  float* attn0 = (float*)(ws + OFF_OPART);
  float* attn1 = (float*)(ws + OFF_ATTN1);
  float* hf = (float*)(ws + OFF_QB);
  u16* hb = (u16*)(ws + OFF_VT);
  u16* f1 = (u16*)(ws + OFF_OPART);
  float* ffn0 = (float*)(ws + OFF_FFN0P);
  float* ffn1 = (float*)(ws + OFF_FFN1P);

  k_cast<<<4096, 256, 0, stream>>>(x, xb, TT * DM / 4);
  k_transpose_cast<<<dim3(32, 32), 256, 0, stream>>>(Wq, WqkvT, DM, DM);
  k_transpose_cast<<<dim3(32, 32), 256, 0, stream>>>(Wk, WqkvT + 1024 * 1024, DM, DM);
  k_transpose_cast<<<dim3(32, 32), 256, 0, stream>>>(Wv, WqkvT + 2048 * 1024, DM, DM);
  k_transpose_cast<<<dim3(32, 32), 256, 0, stream>>>(Wo, WoT, DM, DM);
  k_transpose_cast<<<dim3(128, 32), 256, 0, stream>>>(W1, W1T, DM, DFF);
  k_transpose_cast<<<dim3(32, 128), 256, 0, stream>>>(W2, W2T, DFF, DM);
  k_concat3<<<12, 256, 0, stream>>>(bq, bk, bv, bqkv);

  k_gemm<EPI_QKV3><<<dim3(24, 32, 1), 256, 0, stream>>>(xb, WqkvT, bqkv, ws, TT, 3072,
                                                        DM, DM, 0);

  k_attn_split<<<1024, 256, 0, stream>>>(Qb, Kb, Vt, Opart, ml);
  k_attn_merge<<<4096, 256, 0, stream>>>(Opart, ml, Ob);

  k_gemm<EPI_F32><<<dim3(8, 32, 2), 256, 0, stream>>>(Ob, WoT, bo, attn0, TT, DM,
                                                      DM / 2, DM,
                                                      (size_t)TT * DM);
  k_res_ln<true><<<4096, 256, 0, stream>>>(x, attn0, attn1, g1, b1, hf, hb);

  k_gemm<EPI_GELU><<<dim3(32, 32, 1), 256, 0, stream>>>(hb, W1T, bf1, f1, TT, DFF,
                                                        DM, DM, 0);
  k_gemm<EPI_F32><<<dim3(8, 32, 2), 256, 0, stream>>>(f1, W2T, bf2, ffn0, TT, DM,
                                                      DFF / 2, DFF,
                                                      OFF_FFN1P / 4);
  k_res_ln<false><<<4096, 256, 0, stream>>>(hf, ffn0, ffn1, g2, b2, out, nullptr);
}

// Round 5
// 284.298 us; speedup vs baseline: 1.9362x; 1.0885x over previous
//
#include <hip/hip_runtime.h>
#include <cstdint>
#include <cmath>

typedef unsigned short u16;
typedef unsigned int u32;
typedef unsigned long long u64;
typedef __bf16 bf16x8 __attribute__((ext_vector_type(8)));
typedef float f32x4 __attribute__((ext_vector_type(4)));
typedef float f32x16 __attribute__((ext_vector_type(16)));
typedef int v2i __attribute__((ext_vector_type(2)));

#define AS1 __attribute__((address_space(1)))
#define AS3 __attribute__((address_space(3)))

static constexpr int DM = 1024, DFF = 4096, SS = 2048, HH = 16, HD = 64, TT = 4096;
static constexpr size_t MiB = (size_t)1 << 20;
// workspace offsets (bytes)
static constexpr size_t OFF_WQKVT = 0;         // [3072][1024] bf16, 6 MiB
static constexpr size_t OFF_WOT = 6 * MiB;     // [1024][1024] bf16, 2 MiB
static constexpr size_t OFF_W1T = 8 * MiB;     // [4096][1024] bf16, 8 MiB
static constexpr size_t OFF_W2T = 16 * MiB;    // [1024][4096] bf16, 8 MiB
static constexpr size_t OFF_XB = 24 * MiB;     // [4096][1024] bf16, 8 MiB (reused: Ob)
static constexpr size_t OFF_QB = 32 * MiB;     // [B,H,S,hd] bf16, 8 MiB (reused: hf lo)
static constexpr size_t OFF_KB = 40 * MiB;     // 8 MiB (reused: hf hi)
static constexpr size_t OFF_VT = 48 * MiB;     // blocked V^T, 8 MiB (reused: hb)
static constexpr size_t OFF_FFN1P = 48 * MiB;  // ffn split1 f32, 16 MiB (48-64)
static constexpr size_t OFF_OPART = 64 * MiB;  // [2][32][2048][64] f32, 32 MiB
static constexpr size_t OFF_ATTN1 = 80 * MiB;
static constexpr size_t OFF_ML = 96 * MiB;     // [2][32*2048] float2, 2 MiB
static constexpr size_t OFF_BQKV = 98 * MiB;   // 3072 f32
static constexpr size_t OFF_FFN0P = 0;         // ffn split0 f32, 16 MiB (weights dead)

__device__ __forceinline__ u16 f2bf(float f) {
  union { float f; unsigned u; } c; c.f = f;
  unsigned r = c.u + 0x7fffu + ((c.u >> 16) & 1u);
  return (u16)(r >> 16);
}

__device__ __forceinline__ void gload_lds16(const void* g, void* l) {
  __builtin_amdgcn_global_load_lds((AS1 void*)g, (AS3 void*)l, 16, 0, 0);
}

__device__ __forceinline__ float exp2_(float x) {
#if __has_builtin(__builtin_amdgcn_exp2f)
  return __builtin_amdgcn_exp2f(x);
#else
  return exp2f(x);
#endif
}

__device__ __forceinline__ u32 cvt_pk_bf16(float lo, float hi) {
  u32 r;
  asm("v_cvt_pk_bf16_f32 %0, %1, %2" : "=v"(r) : "v"(lo), "v"(hi));
  return r;
}

__device__ __forceinline__ void lane32_swap(u32& a, u32& b) {
#if __has_builtin(__builtin_amdgcn_permlane32_swap)
  v2i r = __builtin_amdgcn_permlane32_swap((int)a, (int)b, false, false);
  a = (u32)r.x;
  b = (u32)r.y;
#else
  u32 ta = (u32)__shfl_xor((int)a, 32);
  u32 tb = (u32)__shfl_xor((int)b, 32);
  bool hi = (threadIdx.x & 32) != 0;
  u32 na = hi ? tb : a;
  u32 nb = hi ? b : ta;
  a = na;
  b = nb;
#endif
}

__device__ __forceinline__ float cross32_reduce_max(float x) {
  u32 a = __float_as_uint(x), b = a;
  lane32_swap(a, b);
  return fmaxf(__uint_as_float(a), __uint_as_float(b));
}

__device__ __forceinline__ float cross32_reduce_sum(float x) {
  u32 a = __float_as_uint(x), b = a;
  lane32_swap(a, b);
  return __uint_as_float(a) + __uint_as_float(b);
}

// ---------------- cast fp32 -> bf16 ----------------
__global__ __launch_bounds__(256) void k_cast(const float* __restrict__ in,
                                              u16* __restrict__ out, int n4) {
  int i = blockIdx.x * 256 + threadIdx.x;
  if (i < n4) {
    float4 v = ((const float4*)in)[i];
    u64 pk = (u64)f2bf(v.x) | ((u64)f2bf(v.y) << 16) |
             ((u64)f2bf(v.z) << 32) | ((u64)f2bf(v.w) << 48);
    ((u64*)out)[i] = pk;
  }
}

// ------------- transpose+cast: in fp32 [R][C] -> out bf16 [C][R] -------------
__global__ __launch_bounds__(256) void k_transpose_cast(const float* __restrict__ in,
                                                        u16* __restrict__ out,
                                                        int R, int C) {
  __shared__ u16 tile[32][33];
  const int cb = blockIdx.x * 32, rb = blockIdx.y * 32;
  const int tx = threadIdx.x & 31;
  const int ty = threadIdx.x >> 5;
#pragma unroll
  for (int i = 0; i < 4; i++) {
    int r = ty + i * 8;
    tile[r][tx] = f2bf(in[(size_t)(rb + r) * C + cb + tx]);
  }
  __syncthreads();
#pragma unroll
  for (int i = 0; i < 4; i++) {
    int r2 = ty + i * 8;
    out[(size_t)(cb + r2) * R + rb + tx] = tile[tx][r2];
  }
}

// ---------------- concat 3 bias vectors ----------------
__global__ __launch_bounds__(256) void k_concat3(const float* __restrict__ a,
                                                 const float* __restrict__ b,
                                                 const float* __restrict__ c,
                                                 float* __restrict__ out) {
  int i = blockIdx.x * 256 + threadIdx.x;
  if (i < 3072) out[i] = i < 1024 ? a[i] : (i < 2048 ? b[i - 1024] : c[i - 2048]);
}

enum { EPI_F32 = 0, EPI_GELU = 1, EPI_QKV3 = 2 };

// ======== 256x256 8-wave BK=64 deep-pipelined GEMM (full K, no split) ========
// A[M][K], Bt[N][K] bf16 row-major. LDS 128KiB, 2 buffers, XOR-swizzled rows.
template <int EPI>
__global__ __launch_bounds__(512, 2) void k_gemm256(const u16* __restrict__ A,
                                                    const u16* __restrict__ Bt,
                                                    const float* __restrict__ bias,
                                                    void* __restrict__ Cout,
                                                    int N, int K) {
  __shared__ __align__(16) u16 smem[65536];  // 128 KiB: 2 x (A 32K + B 32K)
  const int tid = threadIdx.x;
  const int wid = tid >> 6, lane = tid & 63;
  const int lrow = lane & 15, lgrp = lane >> 4;
  const int wr = wid >> 2, wc = wid & 3;
  const int mrow = blockIdx.y * 256, ncol = blockIdx.x * 256;

  // staging: thread covers (chunk c: row = c*64 + srow, dest granule sgd)
  const int srow = tid >> 3;  // 0..63
  const int sgd = tid & 7;
  const int gsw = (sgd ^ (srow & 7)) << 3;  // pre-swizzled source granule (elems)
  const u16* aS0 = A + (size_t)(mrow + srow) * K + gsw;
  const u16* bS0 = Bt + (size_t)(ncol + srow) * K + gsw;
  const int T = K >> 6;

  auto stageA = [&](int t, int b) {
    u16* dst = smem + b * 32768 + wid * 512;
    const u16* s = aS0 + t * 64;
#pragma unroll
    for (int c = 0; c < 4; ++c) gload_lds16(s + (size_t)c * 64 * K, dst + c * 4096);
  };
  auto stageB = [&](int t, int b) {
    u16* dst = smem + b * 32768 + 16384 + wid * 512;
    const u16* s = bS0 + t * 64;
#pragma unroll
    for (int c = 0; c < 4; ++c) gload_lds16(s + (size_t)c * 64 * K, dst + c * 4096);
  };

  f32x4 acc[8][4];
#pragma unroll
  for (int m = 0; m < 8; ++m)
#pragma unroll
    for (int n = 0; n < 4; ++n) acc[m][n] = (f32x4){0.f, 0.f, 0.f, 0.f};

  stageA(0, 0);
  stageB(0, 0);
  asm volatile("s_waitcnt vmcnt(0)" ::: "memory");
  __builtin_amdgcn_s_barrier();

  const int arow_base = wr * 128 + lrow;
  const int brow_base = wc * 64 + lrow;
  const int aswz = lrow & 7;

  for (int t = 0; t < T; ++t) {
    const int cb = (t & 1) * 32768;
    const u16* Abuf = smem + cb;
    const u16* Bbuf = smem + cb + 16384;
    bf16x8 af[4][2], bfr[4][2];
    // ---- phase 0: read A m-half0 + all B; stage next A; MFMA m0-3 x n0-1 ----
#pragma unroll
    for (int m = 0; m < 4; ++m)
#pragma unroll
      for (int ks = 0; ks < 2; ++ks)
        af[m][ks] = *(const bf16x8*)(Abuf + (arow_base + m * 16) * 64 +
                                     (((ks * 4 + lgrp) ^ aswz) << 3));
#pragma unroll
    for (int n = 0; n < 4; ++n)
#pragma unroll
      for (int ks = 0; ks < 2; ++ks)
        bfr[n][ks] = *(const bf16x8*)(Bbuf + (brow_base + n * 16) * 64 +
                                      (((ks * 4 + lgrp) ^ aswz) << 3));
    if (t + 1 < T) stageA(t + 1, (t + 1) & 1);
    __builtin_amdgcn_s_barrier();
    __builtin_amdgcn_s_setprio(1);
#pragma unroll
    for (int m = 0; m < 4; ++m)
#pragma unroll
      for (int n = 0; n < 2; ++n)
#pragma unroll
        for (int ks = 0; ks < 2; ++ks)
          acc[m][n] = __builtin_amdgcn_mfma_f32_16x16x32_bf16(af[m][ks], bfr[n][ks],
                                                              acc[m][n], 0, 0, 0);
    __builtin_amdgcn_s_setprio(0);
    // ---- phase 1: stage next B; MFMA m0-3 x n2-3 ----
    if (t + 1 < T) stageB(t + 1, (t + 1) & 1);
    __builtin_amdgcn_s_barrier();
    __builtin_amdgcn_s_setprio(1);
#pragma unroll
    for (int m = 0; m < 4; ++m)
#pragma unroll
      for (int n = 2; n < 4; ++n)
#pragma unroll
        for (int ks = 0; ks < 2; ++ks)
          acc[m][n] = __builtin_amdgcn_mfma_f32_16x16x32_bf16(af[m][ks], bfr[n][ks],
                                                              acc[m][n], 0, 0, 0);
    __builtin_amdgcn_s_setprio(0);
    // ---- phase 2: read A m-half1; MFMA m4-7 x n0-1 ----
#pragma unroll
    for (int m = 0; m < 4; ++m)
#pragma unroll
      for (int ks = 0; ks < 2; ++ks)
        af[m][ks] = *(const bf16x8*)(Abuf + (arow_base + (m + 4) * 16) * 64 +
                                     (((ks * 4 + lgrp) ^ aswz) << 3));
    __builtin_amdgcn_s_barrier();
    __builtin_amdgcn_s_setprio(1);
#pragma unroll
    for (int m = 0; m < 4; ++m)
#pragma unroll
      for (int n = 0; n < 2; ++n)
#pragma unroll
        for (int ks = 0; ks < 2; ++ks)
          acc[m + 4][n] = __builtin_amdgcn_mfma_f32_16x16x32_bf16(af[m][ks], bfr[n][ks],
                                                                  acc[m + 4][n], 0, 0, 0);
    __builtin_amdgcn_s_setprio(0);
    // ---- phase 3: MFMA m4-7 x n2-3 ----
    __builtin_amdgcn_s_barrier();
    __builtin_amdgcn_s_setprio(1);
#pragma unroll
    for (int m = 0; m < 4; ++m)
#pragma unroll
      for (int n = 2; n < 4; ++n)
#pragma unroll
        for (int ks = 0; ks < 2; ++ks)
          acc[m + 4][n] = __builtin_amdgcn_mfma_f32_16x16x32_bf16(af[m][ks], bfr[n][ks],
                                                                  acc[m + 4][n], 0, 0, 0);
    __builtin_amdgcn_s_setprio(0);
    // ---- boundary: next tile fully landed (issued >=2 phases ago) ----
    if (t + 1 < T) {
      asm volatile("s_waitcnt vmcnt(0)" ::: "memory");
      __builtin_amdgcn_s_barrier();
      __builtin_amdgcn_sched_barrier(0);
    }
  }

#pragma unroll
  for (int m = 0; m < 8; ++m) {
#pragma unroll
    for (int n = 0; n < 4; ++n) {
      const int row0 = mrow + wr * 128 + m * 16 + lgrp * 4;
      const int col = ncol + wc * 64 + n * 16 + lrow;
      f32x4 v = acc[m][n];
      if constexpr (EPI == EPI_GELU) {
        const float bv = bias[col];
        u16* C = (u16*)Cout;
#pragma unroll
        for (int r = 0; r < 4; r++) {
          float xg = v[r] + bv;
          float gl = 0.5f * xg * (1.0f + erff(xg * 0.70710678118654752f));
          C[(size_t)(row0 + r) * N + col] = f2bf(gl);
        }
      } else if constexpr (EPI == EPI_QKV3) {
        const float bv = bias[col];
        char* wsb = (char*)Cout;
        const int seg = col >> 10, cc = col & 1023;
        const int h = cc >> 6, d = cc & 63;
        if (seg < 2) {
          u16* dst = (u16*)(wsb + (seg == 0 ? OFF_QB : OFF_KB));
#pragma unroll
          for (int r = 0; r < 4; r++) {
            const int row = row0 + r;
            const int b = row >> 11, s = row & 2047;
            dst[((size_t)(b * HH + h) * SS + s) * HD + d] = f2bf(v[r] + bv);
          }
        } else {
          u16* Vt = (u16*)(wsb + OFF_VT);
          const int b = row0 >> 11, s = row0 & 2047;
          u64 pk = (u64)f2bf(v[0] + bv) | ((u64)f2bf(v[1] + bv) << 16) |
                   ((u64)f2bf(v[2] + bv) << 32) | ((u64)f2bf(v[3] + bv) << 48);
          size_t addr = ((size_t)(b * HH + h) * (SS / 64) + (s >> 6)) * 4096 +
                        (size_t)d * 64 + (s & 63);
          *(u64*)&Vt[addr] = pk;
        }
      } else {
        const float bv = bias[col];
        float* C = (float*)Cout;
#pragma unroll
        for (int r = 0; r < 4; r++) C[(size_t)(row0 + r) * N + col] = v[r] + bv;
      }
    }
  }
}

// ---------------- 128x128 bf16 MFMA GEMM (split-K capable) ----------------
template <int EPI>
__global__ __launch_bounds__(256) void k_gemm(const u16* __restrict__ A,
                                              const u16* __restrict__ Bt,
                                              const float* __restrict__ bias,
                                              void* __restrict__ Cout,
                                              int M, int N, int Ksub, int stride,
                                              size_t zoff) {
  __shared__ __align__(16) u16 Alds[128 * 32];
  __shared__ __align__(16) u16 Blds[128 * 32];
  const int tid = threadIdx.x;
  const int wid = tid >> 6, lane = tid & 63;
  const int lrow = lane & 15, lgrp = lane >> 4;
  const int mrow = blockIdx.y * 128, ncol = blockIdx.x * 128;
  const int z = blockIdx.z;
  const int wr = wid >> 1, wc = wid & 1;

  f32x4 acc[4][4];
#pragma unroll
  for (int m = 0; m < 4; m++)
#pragma unroll
    for (int n = 0; n < 4; n++) acc[m][n] = (f32x4){0.f, 0.f, 0.f, 0.f};

  const int r0 = tid >> 2;
  const int c0 = (tid & 3) * 8;
  const u16* aBase = A + (size_t)(mrow + r0) * stride + (size_t)z * Ksub + c0;
  const u16* bBase = Bt + (size_t)(ncol + r0) * stride + (size_t)z * Ksub + c0;
  char* la = (char*)Alds + wid * 1024;
  char* lb = (char*)Blds + wid * 1024;

  for (int k0 = 0; k0 < Ksub; k0 += 32) {
    gload_lds16(aBase + k0, la);
    gload_lds16(aBase + (size_t)64 * stride + k0, la + 4096);
    gload_lds16(bBase + k0, lb);
    gload_lds16(bBase + (size_t)64 * stride + k0, lb + 4096);
    __syncthreads();
    bf16x8 af[4], bfr[4];
#pragma unroll
    for (int m = 0; m < 4; m++)
      af[m] = *(const bf16x8*)&Alds[(wr * 64 + m * 16 + lrow) * 32 + lgrp * 8];
#pragma unroll
    for (int n = 0; n < 4; n++)
      bfr[n] = *(const bf16x8*)&Blds[(wc * 64 + n * 16 + lrow) * 32 + lgrp * 8];
#pragma unroll
    for (int m = 0; m < 4; m++)
#pragma unroll
      for (int n = 0; n < 4; n++)
        acc[m][n] = __builtin_amdgcn_mfma_f32_16x16x32_bf16(af[m], bfr[n], acc[m][n], 0, 0, 0);
    __syncthreads();
  }

#pragma unroll
  for (int m = 0; m < 4; m++) {
#pragma unroll
    for (int n = 0; n < 4; n++) {
      const int row0 = mrow + wr * 64 + m * 16 + lgrp * 4;
      const int col = ncol + wc * 64 + n * 16 + lrow;
      f32x4 v = acc[m][n];
      if constexpr (EPI == EPI_F32) {
        const float bv = (z == 0) ? bias[col] : 0.0f;
        float* C = (float*)Cout + (size_t)z * zoff;
#pragma unroll
        for (int r = 0; r < 4; r++) C[(size_t)(row0 + r) * N + col] = v[r] + bv;
      }
    }
  }
}

// ---------------- flash attention, KV-split=2, LDS-staged K/V ----------------
__global__ __launch_bounds__(256) void k_attn_split(const u16* __restrict__ Q,
                                                    const u16* __restrict__ K,
                                                    const u16* __restrict__ Vt,
                                                    float* __restrict__ Opart,
                                                    float* __restrict__ ml) {
  __shared__ __align__(16) u16 Kl[2][4096];
  __shared__ __align__(16) u16 Vl[2][4096];
  const int tid = threadIdx.x, wid = tid >> 6, lane = tid & 63;
  const int ql = lane & 31, hi = lane >> 5;
  const int bx = blockIdx.x;
  const int split = bx >> 9, bh = (bx >> 4) & 31, qblk = bx & 15;
  const int qbase = qblk * 128 + wid * 32;
  const int kvS = split * 1024;
  const u16* Qh = Q + (size_t)bh * SS * HD;
  const u16* Kh = K + (size_t)bh * SS * HD;
  const u16* Vh = Vt + (size_t)bh * HD * SS;

  const int lrow3 = lane >> 3;
  const int lin = lrow3 * 128 + ((((lane & 7) << 4)) ^ (lrow3 << 4));
  const int kswz = (ql & 7) << 4;

  auto stage = [&](int kv0, int bufi) {
    const char* Ks = (const char*)Kh + (size_t)kv0 * 128 + wid * 2048 + lin;
    const char* Vs = (const char*)Vh + ((size_t)(kv0 >> 6)) * 8192 + wid * 2048 + lin;
    char* kd = (char*)&Kl[bufi][0] + wid * 2048;
    char* vd = (char*)&Vl[bufi][0] + wid * 2048;
    gload_lds16(Ks, kd);
    gload_lds16(Ks + 1024, kd + 1024);
    gload_lds16(Vs, vd);
    gload_lds16(Vs + 1024, vd + 1024);
  };

  bf16x8 qf[4];
#pragma unroll
  for (int j = 0; j < 4; j++)
    qf[j] = *(const bf16x8*)&Qh[(size_t)(qbase + ql) * HD + j * 16 + hi * 8];

  f32x16 oacc0, oacc1;
#pragma unroll
  for (int r = 0; r < 16; r++) { oacc0[r] = 0.f; oacc1[r] = 0.f; }
  float m2 = -1e30f;
  float lsum = 0.f;
  const float cs = 0.125f * 1.44269504f;

  auto tileC = [&](int bufi, int tt) {
    const char* Kb = (const char*)&Kl[bufi][0];
    const char* Vb = (const char*)&Vl[bufi][0];
    bf16x8 kf[4];
#pragma unroll
    for (int j = 0; j < 4; j++)
      kf[j] = *(const bf16x8*)(Kb + (tt * 32 + ql) * 128 + ((j * 32 + hi * 16) ^ kswz));

    f32x16 s;
#pragma unroll
    for (int r = 0; r < 16; r++) s[r] = 0.f;
#pragma unroll
    for (int j = 0; j < 4; j++)
      s = __builtin_amdgcn_mfma_f32_32x32x16_bf16(kf[j], qf[j], s, 0, 0, 0);

    float t0 = fmaxf(fmaxf(s[0], s[1]), fmaxf(s[2], s[3]));
    float t1 = fmaxf(fmaxf(s[4], s[5]), fmaxf(s[6], s[7]));
    float t2 = fmaxf(fmaxf(s[8], s[9]), fmaxf(s[10], s[11]));
    float t3 = fmaxf(fmaxf(s[12], s[13]), fmaxf(s[14], s[15]));
    float tmax = cross32_reduce_max(fmaxf(fmaxf(t0, t1), fmaxf(t2, t3))) * cs;

    if (!__all(tmax - m2 <= 8.f)) {
      float m2n = fmaxf(m2, tmax);
      float al = exp2_(m2 - m2n);
      m2 = m2n;
      lsum *= al;
#pragma unroll
      for (int r = 0; r < 16; r++) { oacc0[r] *= al; oacc1[r] *= al; }
    }

    float p[16];
    float ts = 0.f;
#pragma unroll
    for (int r = 0; r < 16; r++) {
      p[r] = exp2_(fmaf(s[r], cs, -m2));
      ts += p[r];
    }
    lsum += cross32_reduce_sum(ts);

    u32 w01 = cvt_pk_bf16(p[0], p[1]), w23 = cvt_pk_bf16(p[2], p[3]);
    u32 w45 = cvt_pk_bf16(p[4], p[5]), w67 = cvt_pk_bf16(p[6], p[7]);
    u32 w89 = cvt_pk_bf16(p[8], p[9]), wab = cvt_pk_bf16(p[10], p[11]);
    u32 wcd = cvt_pk_bf16(p[12], p[13]), wef = cvt_pk_bf16(p[14], p[15]);
    lane32_swap(w01, w45);
    lane32_swap(w23, w67);
    lane32_swap(w89, wcd);
    lane32_swap(wab, wef);
    union { u32 w[4]; bf16x8 v; } f0, f1;
    f0.w[0] = w01; f0.w[1] = w23; f0.w[2] = w45; f0.w[3] = w67;
    f1.w[0] = w89; f1.w[1] = wab; f1.w[2] = wcd; f1.w[3] = wef;

    bf16x8 vf[4];
#pragma unroll
    for (int u = 0; u < 4; u++)
      vf[u] = *(const bf16x8*)(Vb + ((u >> 1) * 32 + ql) * 128 +
                               ((tt * 64 + (u & 1) * 32 + hi * 16) ^ kswz));

    oacc0 = __builtin_amdgcn_mfma_f32_32x32x16_bf16(vf[0], f0.v, oacc0, 0, 0, 0);
    oacc0 = __builtin_amdgcn_mfma_f32_32x32x16_bf16(vf[1], f1.v, oacc0, 0, 0, 0);
    oacc1 = __builtin_amdgcn_mfma_f32_32x32x16_bf16(vf[2], f0.v, oacc1, 0, 0, 0);
    oacc1 = __builtin_amdgcn_mfma_f32_32x32x16_bf16(vf[3], f1.v, oacc1, 0, 0, 0);
  };

  stage(kvS, 0);
  __syncthreads();
  int cur = 0;
  for (int it = 0; it < 16; ++it) {
    if (it + 1 < 16) stage(kvS + (it + 1) * 64, cur ^ 1);
    tileC(cur, 0);
    tileC(cur, 1);
    __syncthreads();
    cur ^= 1;
  }

  const int rowidx = bh * SS + qbase + ql;
  float* Orow = Opart + ((size_t)split * 32 * SS + rowidx) * HD;
  auto storeAcc = [&](const f32x16& a, int dbase) {
#pragma unroll
    for (int t = 0; t < 4; t++)
      *(float4*)&Orow[dbase + 4 * hi + 8 * t] =
          make_float4(a[4 * t], a[4 * t + 1], a[4 * t + 2], a[4 * t + 3]);
  };
  storeAcc(oacc0, 0);
  storeAcc(oacc1, 32);
  if (hi == 0)
    *(float2*)&ml[((size_t)split * 32 * SS + rowidx) * 2] = make_float2(m2, lsum);
}

// ---------------- merge the two KV-split partials -> bf16 O [T][DM] ----------------
__global__ __launch_bounds__(256) void k_attn_merge(const float* __restrict__ Opart,
                                                    const float* __restrict__ ml,
                                                    u16* __restrict__ O) {
  const int g = blockIdx.x * 256 + threadIdx.x;
  const int row = g >> 4, dseg = g & 15;
  const float2 m0 = ((const float2*)ml)[row];
  const float2 m1 = ((const float2*)ml)[32 * SS + row];
  const float mm = fmaxf(m0.x, m1.x);
  const float w0 = exp2f(m0.x - mm), w1 = exp2f(m1.x - mm);
  const float inv = 1.0f / (m0.y * w0 + m1.y * w1);
  const float4 o0 = ((const float4*)Opart)[(size_t)row * 16 + dseg];
  const float4 o1 = ((const float4*)Opart)[(size_t)(32 * SS + row) * 16 + dseg];
  const float a = (o0.x * w0 + o1.x * w1) * inv;
  const float b = (o0.y * w0 + o1.y * w1) * inv;
  const float c = (o0.z * w0 + o1.z * w1) * inv;
  const float d = (o0.w * w0 + o1.w * w1) * inv;
  const int bh = row >> 11, s = row & 2047;
  const int bb = bh >> 4, h = bh & 15;
  u64 pk = (u64)f2bf(a) | ((u64)f2bf(b) << 16) | ((u64)f2bf(c) << 32) | ((u64)f2bf(d) << 48);
  *(u64*)&O[((size_t)(bb * SS + s) * DM) + h * HD + dseg * 4] = pk;
}

// ---------------- fused residual(2-way) + layernorm ----------------
template <bool WB>
__global__ __launch_bounds__(256) void k_res_ln(const float* __restrict__ X,
                                                const float* __restrict__ Y0,
                                                const float* __restrict__ Y1,
                                                const float* __restrict__ gw,
                                                const float* __restrict__ bw,
                                                float* __restrict__ outf,
                                                u16* __restrict__ outb) {
  const int row = blockIdx.x, t = threadIdx.x;
  const float4 xv = ((const float4*)(X + (size_t)row * DM))[t];
  const float4 y0 = ((const float4*)(Y0 + (size_t)row * DM))[t];
  const float4 y1 = ((const float4*)(Y1 + (size_t)row * DM))[t];
  float v0 = xv.x + y0.x + y1.x, v1 = xv.y + y0.y + y1.y;
  float v2 = xv.z + y0.z + y1.z, v3 = xv.w + y0.w + y1.w;
  float s = v0 + v1 + v2 + v3;
  float s2 = v0 * v0 + v1 * v1 + v2 * v2 + v3 * v3;
#pragma unroll
  for (int off = 32; off >= 1; off >>= 1) {
    s += __shfl_down(s, off);
    s2 += __shfl_down(s2, off);
  }
  __shared__ float ps[4], ps2[4];
  const int wid = t >> 6, lane = t & 63;
  if (lane == 0) { ps[wid] = s; ps2[wid] = s2; }
  __syncthreads();
  const float ts = ps[0] + ps[1] + ps[2] + ps[3];
  const float ts2 = ps2[0] + ps2[1] + ps2[2] + ps2[3];
  const float mu = ts * (1.f / 1024.f);
  const float rs = rsqrtf(ts2 * (1.f / 1024.f) - mu * mu + 1e-5f);
  const float4 g4 = ((const float4*)gw)[t];
  const float4 b4 = ((const float4*)bw)[t];
  float o0 = (v0 - mu) * rs * g4.x + b4.x;
  float o1 = (v1 - mu) * rs * g4.y + b4.y;
  float o2 = (v2 - mu) * rs * g4.z + b4.z;
  float o3 = (v3 - mu) * rs * g4.w + b4.w;
  ((float4*)(outf + (size_t)row * DM))[t] = make_float4(o0, o1, o2, o3);
  if constexpr (WB) {
    u64 pk = (u64)f2bf(o0) | ((u64)f2bf(o1) << 16) | ((u64)f2bf(o2) << 32) |
             ((u64)f2bf(o3) << 48);
    ((u64*)(outb + (size_t)row * DM))[t] = pk;
  }
}

extern "C" void kernel_launch(void* const* d_in, const int* in_sizes, int n_in,
                              void* d_out, int out_size, void* d_ws, size_t ws_size,
                              hipStream_t stream) {
  const float* x = (const float*)d_in[0];
  const float* Wq = (const float*)d_in[1];
  const float* bq = (const float*)d_in[2];
  const float* Wk = (const float*)d_in[3];
  const float* bk = (const float*)d_in[4];
  const float* Wv = (const float*)d_in[5];
  const float* bv = (const float*)d_in[6];
  const float* Wo = (const float*)d_in[7];
  const float* bo = (const float*)d_in[8];
  const float* g1 = (const float*)d_in[9];
  const float* b1 = (const float*)d_in[10];
  const float* g2 = (const float*)d_in[11];
  const float* b2 = (const float*)d_in[12];
  const float* W1 = (const float*)d_in[13];
  const float* bf1 = (const float*)d_in[14];
  const float* W2 = (const float*)d_in[15];
  const float* bf2 = (const float*)d_in[16];
  float* out = (float*)d_out;

  if (ws_size < 99 * MiB) return;
  char* ws = (char*)d_ws;
  u16* WqkvT = (u16*)(ws + OFF_WQKVT);
  u16* WoT = (u16*)(ws + OFF_WOT);
  u16* W1T = (u16*)(ws + OFF_W1T);
  u16* W2T = (u16*)(ws + OFF_W2T);
  u16* xb = (u16*)(ws + OFF_XB);
  u16* Qb = (u16*)(ws + OFF_QB);
  u16* Kb = (u16*)(ws + OFF_KB);
  u16* Vt = (u16*)(ws + OFF_VT);
  u16* Ob = (u16*)(ws + OFF_XB);
  float* Opart = (float*)(ws + OFF_OPART);
  float* ml = (float*)(ws + OFF_ML);
  float* bqkv = (float*)(ws + OFF_BQKV);
  float* attn0 = (float*)(ws + OFF_OPART);
  float* attn1 = (float*)(ws + OFF_ATTN1);
  float* hf = (float*)(ws + OFF_QB);
  u16* hb = (u16*)(ws + OFF_VT);
  u16* f1 = (u16*)(ws + OFF_OPART);
  float* ffn0 = (float*)(ws + OFF_FFN0P);
  float* ffn1 = (float*)(ws + OFF_FFN1P);

  k_cast<<<4096, 256, 0, stream>>>(x, xb, TT * DM / 4);
  k_transpose_cast<<<dim3(32, 32), 256, 0, stream>>>(Wq, WqkvT, DM, DM);
  k_transpose_cast<<<dim3(32, 32), 256, 0, stream>>>(Wk, WqkvT + 1024 * 1024, DM, DM);
  k_transpose_cast<<<dim3(32, 32), 256, 0, stream>>>(Wv, WqkvT + 2048 * 1024, DM, DM);
  k_transpose_cast<<<dim3(32, 32), 256, 0, stream>>>(Wo, WoT, DM, DM);
  k_transpose_cast<<<dim3(128, 32), 256, 0, stream>>>(W1, W1T, DM, DFF);
  k_transpose_cast<<<dim3(32, 128), 256, 0, stream>>>(W2, W2T, DFF, DM);
  k_concat3<<<12, 256, 0, stream>>>(bq, bk, bv, bqkv);

  // fused QKV projection on the 256^2 pipelined kernel
  k_gemm256<EPI_QKV3><<<dim3(12, 16), 512, 0, stream>>>(xb, WqkvT, bqkv, ws, 3072, DM);

  k_attn_split<<<1024, 256, 0, stream>>>(Qb, Kb, Vt, Opart, ml);
  k_attn_merge<<<4096, 256, 0, stream>>>(Opart, ml, Ob);

  // Wo projection, split-K=2 (128^2 kernel: grid occupancy better at N=1024)
  k_gemm<EPI_F32><<<dim3(8, 32, 2), 256, 0, stream>>>(Ob, WoT, bo, attn0, TT, DM,
                                                      DM / 2, DM,
                                                      (size_t)TT * DM);
  k_res_ln<true><<<4096, 256, 0, stream>>>(x, attn0, attn1, g1, b1, hf, hb);

  // FFN1 on the 256^2 pipelined kernel (gelu epilogue)
  k_gemm256<EPI_GELU><<<dim3(16, 16), 512, 0, stream>>>(hb, W1T, bf1, f1, DFF, DM);

  // FFN2, split-K=2
  k_gemm<EPI_F32><<<dim3(8, 32, 2), 256, 0, stream>>>(f1, W2T, bf2, ffn0, TT, DM,
                                                      DFF / 2, DFF,
                                                      OFF_FFN1P / 4);
  k_res_ln<false><<<4096, 256, 0, stream>>>(hf, ffn0, ffn1, g2, b2, out, nullptr);
}

// Round 6
// 260.713 us; speedup vs baseline: 2.1113x; 1.0905x over previous
//
#include <hip/hip_runtime.h>
#include <cstdint>
#include <cmath>

typedef unsigned short u16;
typedef unsigned int u32;
typedef unsigned long long u64;
typedef __bf16 bf16x8 __attribute__((ext_vector_type(8)));
typedef float f32x4 __attribute__((ext_vector_type(4)));
typedef float f32x16 __attribute__((ext_vector_type(16)));
typedef int v2i __attribute__((ext_vector_type(2)));

#define AS1 __attribute__((address_space(1)))
#define AS3 __attribute__((address_space(3)))

static constexpr int DM = 1024, DFF = 4096, SS = 2048, HH = 16, HD = 64, TT = 4096;
static constexpr size_t MiB = (size_t)1 << 20;
static constexpr size_t OFF_WQKVT = 0;         // [3072][1024] bf16, 6 MiB
static constexpr size_t OFF_WOT = 6 * MiB;     // [1024][1024] bf16, 2 MiB
static constexpr size_t OFF_W1T = 8 * MiB;     // [4096][1024] bf16, 8 MiB
static constexpr size_t OFF_W2T = 16 * MiB;    // [1024][4096] bf16, 8 MiB
static constexpr size_t OFF_XB = 24 * MiB;     // [4096][1024] bf16 (reused: Ob)
static constexpr size_t OFF_QB = 32 * MiB;     // (reused: hf lo)
static constexpr size_t OFF_KB = 40 * MiB;     // (reused: hf hi)
static constexpr size_t OFF_VT = 48 * MiB;     // blocked V^T (reused: hb)
static constexpr size_t OFF_FFN1P = 48 * MiB;  // ffn split1 f32, 16 MiB
static constexpr size_t OFF_OPART = 64 * MiB;  // 32 MiB (reused: attn0/attn1, f1)
static constexpr size_t OFF_ATTN1 = 80 * MiB;
static constexpr size_t OFF_ML = 96 * MiB;     // 2 MiB
static constexpr size_t OFF_BQKV = 98 * MiB;   // 3072 f32
static constexpr size_t OFF_FFN0P = 0;         // ffn split0 f32 (weights dead)

__device__ __forceinline__ u16 f2bf(float f) {
  union { float f; unsigned u; } c; c.f = f;
  unsigned r = c.u + 0x7fffu + ((c.u >> 16) & 1u);
  return (u16)(r >> 16);
}

__device__ __forceinline__ void gload_lds16(const void* g, void* l) {
  __builtin_amdgcn_global_load_lds((AS1 void*)g, (AS3 void*)l, 16, 0, 0);
}

__device__ __forceinline__ float exp2_(float x) {
#if __has_builtin(__builtin_amdgcn_exp2f)
  return __builtin_amdgcn_exp2f(x);
#else
  return exp2f(x);
#endif
}

__device__ __forceinline__ u32 cvt_pk_bf16(float lo, float hi) {
  u32 r;
  asm("v_cvt_pk_bf16_f32 %0, %1, %2" : "=v"(r) : "v"(lo), "v"(hi));
  return r;
}

__device__ __forceinline__ void lane32_swap(u32& a, u32& b) {
#if __has_builtin(__builtin_amdgcn_permlane32_swap)
  v2i r = __builtin_amdgcn_permlane32_swap((int)a, (int)b, false, false);
  a = (u32)r.x;
  b = (u32)r.y;
#else
  u32 ta = (u32)__shfl_xor((int)a, 32);
  u32 tb = (u32)__shfl_xor((int)b, 32);
  bool hi = (threadIdx.x & 32) != 0;
  u32 na = hi ? tb : a;
  u32 nb = hi ? b : ta;
  a = na;
  b = nb;
#endif
}

__device__ __forceinline__ float cross32_reduce_max(float x) {
  u32 a = __float_as_uint(x), b = a;
  lane32_swap(a, b);
  return fmaxf(__uint_as_float(a), __uint_as_float(b));
}

__device__ __forceinline__ float cross32_reduce_sum(float x) {
  u32 a = __float_as_uint(x), b = a;
  lane32_swap(a, b);
  return __uint_as_float(a) + __uint_as_float(b);
}

// XCD-chunked bijective swizzle (grid must be %8==0 or handled by q8 floor; all ours are %8==0)
__device__ __forceinline__ int xcd_swizzle(int bid, int nwg) {
  int q8 = nwg >> 3;
  return (bid & 7) * q8 + (bid >> 3);
}

// ---------------- cast fp32 -> bf16 ----------------
__global__ __launch_bounds__(256) void k_cast(const float* __restrict__ in,
                                              u16* __restrict__ out, int n4) {
  int i = blockIdx.x * 256 + threadIdx.x;
  if (i < n4) {
    float4 v = ((const float4*)in)[i];
    u64 pk = (u64)f2bf(v.x) | ((u64)f2bf(v.y) << 16) |
             ((u64)f2bf(v.z) << 32) | ((u64)f2bf(v.w) << 48);
    ((u64*)out)[i] = pk;
  }
}

// ------------- transpose+cast: in fp32 [R][C] -> out bf16 [C][R] -------------
__global__ __launch_bounds__(256) void k_transpose_cast(const float* __restrict__ in,
                                                        u16* __restrict__ out,
                                                        int R, int C) {
  __shared__ u16 tile[32][33];
  const int cb = blockIdx.x * 32, rb = blockIdx.y * 32;
  const int tx = threadIdx.x & 31;
  const int ty = threadIdx.x >> 5;
#pragma unroll
  for (int i = 0; i < 4; i++) {
    int r = ty + i * 8;
    tile[r][tx] = f2bf(in[(size_t)(rb + r) * C + cb + tx]);
  }
  __syncthreads();
#pragma unroll
  for (int i = 0; i < 4; i++) {
    int r2 = ty + i * 8;
    out[(size_t)(cb + r2) * R + rb + tx] = tile[tx][r2];
  }
}

// ---------------- concat 3 bias vectors ----------------
__global__ __launch_bounds__(256) void k_concat3(const float* __restrict__ a,
                                                 const float* __restrict__ b,
                                                 const float* __restrict__ c,
                                                 float* __restrict__ out) {
  int i = blockIdx.x * 256 + threadIdx.x;
  if (i < 3072) out[i] = i < 1024 ? a[i] : (i < 2048 ? b[i - 1024] : c[i - 2048]);
}

enum { EPI_F32 = 0, EPI_GELU = 1, EPI_QKV3 = 2 };

// ======== 256x256 8-wave BK=64 deep-pipelined GEMM (full K), XCD-swizzled ========
template <int EPI>
__global__ __launch_bounds__(512) void k_gemm256(const u16* __restrict__ A,
                                                 const u16* __restrict__ Bt,
                                                 const float* __restrict__ bias,
                                                 void* __restrict__ Cout,
                                                 int N, int K, int nx) {
  __shared__ __align__(16) u16 smem[65536];  // 128 KiB
  const int tid = threadIdx.x;
  const int wid = tid >> 6, lane = tid & 63;
  const int lrow = lane & 15, lgrp = lane >> 4;
  const int wr = wid >> 2, wc = wid & 3;
  const int swz = xcd_swizzle(blockIdx.x, gridDim.x);
  const int mrow = (swz / nx) * 256, ncol = (swz % nx) * 256;

  const int srow = tid >> 3;
  const int sgd = tid & 7;
  const int gsw = (sgd ^ (srow & 7)) << 3;
  const u16* aS0 = A + (size_t)(mrow + srow) * K + gsw;
  const u16* bS0 = Bt + (size_t)(ncol + srow) * K + gsw;
  const int T = K >> 6;

  auto stageA = [&](int t, int b) {
    u16* dst = smem + b * 32768 + wid * 512;
    const u16* s = aS0 + t * 64;
#pragma unroll
    for (int c = 0; c < 4; ++c) gload_lds16(s + (size_t)c * 64 * K, dst + c * 4096);
  };
  auto stageB = [&](int t, int b) {
    u16* dst = smem + b * 32768 + 16384 + wid * 512;
    const u16* s = bS0 + t * 64;
#pragma unroll
    for (int c = 0; c < 4; ++c) gload_lds16(s + (size_t)c * 64 * K, dst + c * 4096);
  };

  f32x4 acc[8][4];
#pragma unroll
  for (int m = 0; m < 8; ++m)
#pragma unroll
    for (int n = 0; n < 4; ++n) acc[m][n] = (f32x4){0.f, 0.f, 0.f, 0.f};

  stageA(0, 0);
  stageB(0, 0);
  asm volatile("s_waitcnt vmcnt(0)" ::: "memory");
  __builtin_amdgcn_s_barrier();

  const int arow_base = wr * 128 + lrow;
  const int brow_base = wc * 64 + lrow;
  const int aswz = lrow & 7;

  for (int t = 0; t < T; ++t) {
    const int cb = (t & 1) * 32768;
    const u16* Abuf = smem + cb;
    const u16* Bbuf = smem + cb + 16384;
    bf16x8 af[4][2], bfr[4][2];
#pragma unroll
    for (int m = 0; m < 4; ++m)
#pragma unroll
      for (int ks = 0; ks < 2; ++ks)
        af[m][ks] = *(const bf16x8*)(Abuf + (arow_base + m * 16) * 64 +
                                     (((ks * 4 + lgrp) ^ aswz) << 3));
#pragma unroll
    for (int n = 0; n < 4; ++n)
#pragma unroll
      for (int ks = 0; ks < 2; ++ks)
        bfr[n][ks] = *(const bf16x8*)(Bbuf + (brow_base + n * 16) * 64 +
                                      (((ks * 4 + lgrp) ^ aswz) << 3));
    if (t + 1 < T) stageA(t + 1, (t + 1) & 1);
    __builtin_amdgcn_s_barrier();
    __builtin_amdgcn_s_setprio(1);
#pragma unroll
    for (int m = 0; m < 4; ++m)
#pragma unroll
      for (int n = 0; n < 2; ++n)
#pragma unroll
        for (int ks = 0; ks < 2; ++ks)
          acc[m][n] = __builtin_amdgcn_mfma_f32_16x16x32_bf16(af[m][ks], bfr[n][ks],
                                                              acc[m][n], 0, 0, 0);
    __builtin_amdgcn_s_setprio(0);
    if (t + 1 < T) stageB(t + 1, (t + 1) & 1);
    __builtin_amdgcn_s_barrier();
    __builtin_amdgcn_s_setprio(1);
#pragma unroll
    for (int m = 0; m < 4; ++m)
#pragma unroll
      for (int n = 2; n < 4; ++n)
#pragma unroll
        for (int ks = 0; ks < 2; ++ks)
          acc[m][n] = __builtin_amdgcn_mfma_f32_16x16x32_bf16(af[m][ks], bfr[n][ks],
                                                              acc[m][n], 0, 0, 0);
    __builtin_amdgcn_s_setprio(0);
#pragma unroll
    for (int m = 0; m < 4; ++m)
#pragma unroll
      for (int ks = 0; ks < 2; ++ks)
        af[m][ks] = *(const bf16x8*)(Abuf + (arow_base + (m + 4) * 16) * 64 +
                                     (((ks * 4 + lgrp) ^ aswz) << 3));
    __builtin_amdgcn_s_barrier();
    __builtin_amdgcn_s_setprio(1);
#pragma unroll
    for (int m = 0; m < 4; ++m)
#pragma unroll
      for (int n = 0; n < 2; ++n)
#pragma unroll
        for (int ks = 0; ks < 2; ++ks)
          acc[m + 4][n] = __builtin_amdgcn_mfma_f32_16x16x32_bf16(af[m][ks], bfr[n][ks],
                                                                  acc[m + 4][n], 0, 0, 0);
    __builtin_amdgcn_s_setprio(0);
    __builtin_amdgcn_s_barrier();
    __builtin_amdgcn_s_setprio(1);
#pragma unroll
    for (int m = 0; m < 4; ++m)
#pragma unroll
      for (int n = 2; n < 4; ++n)
#pragma unroll
        for (int ks = 0; ks < 2; ++ks)
          acc[m + 4][n] = __builtin_amdgcn_mfma_f32_16x16x32_bf16(af[m][ks], bfr[n][ks],
                                                                  acc[m + 4][n], 0, 0, 0);
    __builtin_amdgcn_s_setprio(0);
    if (t + 1 < T) {
      asm volatile("s_waitcnt vmcnt(0)" ::: "memory");
      __builtin_amdgcn_s_barrier();
      __builtin_amdgcn_sched_barrier(0);
    }
  }

#pragma unroll
  for (int m = 0; m < 8; ++m) {
#pragma unroll
    for (int n = 0; n < 4; ++n) {
      const int row0 = mrow + wr * 128 + m * 16 + lgrp * 4;
      const int col = ncol + wc * 64 + n * 16 + lrow;
      f32x4 v = acc[m][n];
      if constexpr (EPI == EPI_GELU) {
        const float bv = bias[col];
        u16* C = (u16*)Cout;
#pragma unroll
        for (int r = 0; r < 4; r++) {
          float xg = v[r] + bv;
          float gl = 0.5f * xg * (1.0f + erff(xg * 0.70710678118654752f));
          C[(size_t)(row0 + r) * N + col] = f2bf(gl);
        }
      } else if constexpr (EPI == EPI_QKV3) {
        const float bv = bias[col];
        char* wsb = (char*)Cout;
        const int seg = col >> 10, cc = col & 1023;
        const int h = cc >> 6, d = cc & 63;
        if (seg < 2) {
          u16* dst = (u16*)(wsb + (seg == 0 ? OFF_QB : OFF_KB));
#pragma unroll
          for (int r = 0; r < 4; r++) {
            const int row = row0 + r;
            const int b = row >> 11, s = row & 2047;
            dst[((size_t)(b * HH + h) * SS + s) * HD + d] = f2bf(v[r] + bv);
          }
        } else {
          u16* Vt = (u16*)(wsb + OFF_VT);
          const int b = row0 >> 11, s = row0 & 2047;
          u64 pk = (u64)f2bf(v[0] + bv) | ((u64)f2bf(v[1] + bv) << 16) |
                   ((u64)f2bf(v[2] + bv) << 32) | ((u64)f2bf(v[3] + bv) << 48);
          size_t addr = ((size_t)(b * HH + h) * (SS / 64) + (s >> 6)) * 4096 +
                        (size_t)d * 64 + (s & 63);
          *(u64*)&Vt[addr] = pk;
        }
      } else {
        const float bv = bias[col];
        float* C = (float*)Cout;
#pragma unroll
        for (int r = 0; r < 4; r++) C[(size_t)(row0 + r) * N + col] = v[r] + bv;
      }
    }
  }
}

// ======== 256x128 8-wave BK=64 deep-pipelined GEMM, split-K, XCD-swizzled ========
// A[M][stride] (K-chunk z at z*Ksub), Bt[N][stride]. Writes f32 partial z to
// Cout + z*zoff; bias added only for z==0. grid 1-D = nx*ny*nz.
__global__ __launch_bounds__(512) void k_gemmMN(const u16* __restrict__ A,
                                                const u16* __restrict__ Bt,
                                                const float* __restrict__ bias,
                                                float* __restrict__ Cout,
                                                int N, int Ksub, int stride,
                                                size_t zoff, int nx, int ny) {
  __shared__ __align__(16) u16 smem[49152];  // 96 KiB: 2 x (A 32K + B 16K bytes)
  const int tid = threadIdx.x;
  const int wid = tid >> 6, lane = tid & 63;
  const int lrow = lane & 15, lgrp = lane >> 4;
  const int wr = wid >> 2, wc = wid & 3;  // wave grid 2M x 4N
  const int swz = xcd_swizzle(blockIdx.x, gridDim.x);
  const int bx = swz % nx;
  const int by = (swz / nx) % ny;
  const int bz = swz / (nx * ny);
  const int mrow = by * 256, ncol = bx * 128;

  const int srow = tid >> 3;
  const int sgd = tid & 7;
  const int gsw = (sgd ^ (srow & 7)) << 3;
  const u16* aS0 = A + (size_t)(mrow + srow) * stride + (size_t)bz * Ksub + gsw;
  const u16* bS0 = Bt + (size_t)(ncol + srow) * stride + (size_t)bz * Ksub + gsw;
  const int T = Ksub >> 6;

  auto stageA = [&](int t, int b) {
    u16* dst = smem + b * 24576 + wid * 512;
    const u16* s = aS0 + t * 64;
#pragma unroll
    for (int c = 0; c < 4; ++c) gload_lds16(s + (size_t)c * 64 * stride, dst + c * 4096);
  };
  auto stageB = [&](int t, int b) {
    u16* dst = smem + b * 24576 + 16384 + wid * 512;
    const u16* s = bS0 + t * 64;
#pragma unroll
    for (int c = 0; c < 2; ++c) gload_lds16(s + (size_t)c * 64 * stride, dst + c * 4096);
  };

  f32x4 acc[8][2];
#pragma unroll
  for (int m = 0; m < 8; ++m)
#pragma unroll
    for (int n = 0; n < 2; ++n) acc[m][n] = (f32x4){0.f, 0.f, 0.f, 0.f};

  stageA(0, 0);
  stageB(0, 0);
  asm volatile("s_waitcnt vmcnt(0)" ::: "memory");
  __builtin_amdgcn_s_barrier();

  const int arow_base = wr * 128 + lrow;
  const int brow_base = wc * 32 + lrow;
  const int aswz = lrow & 7;

  for (int t = 0; t < T; ++t) {
    const int cb = (t & 1) * 24576;
    const u16* Abuf = smem + cb;
    const u16* Bbuf = smem + cb + 16384;
    bf16x8 af[4][2], bfr[2][2];
    // phase 0: read A m0-3 + all B; stage next A; MFMA m0-3 x n0
#pragma unroll
    for (int m = 0; m < 4; ++m)
#pragma unroll
      for (int ks = 0; ks < 2; ++ks)
        af[m][ks] = *(const bf16x8*)(Abuf + (arow_base + m * 16) * 64 +
                                     (((ks * 4 + lgrp) ^ aswz) << 3));
#pragma unroll
    for (int n = 0; n < 2; ++n)
#pragma unroll
      for (int ks = 0; ks < 2; ++ks)
        bfr[n][ks] = *(const bf16x8*)(Bbuf + (brow_base + n * 16) * 64 +
                                      (((ks * 4 + lgrp) ^ aswz) << 3));
    if (t + 1 < T) stageA(t + 1, (t + 1) & 1);
    __builtin_amdgcn_s_barrier();
    __builtin_amdgcn_s_setprio(1);
#pragma unroll
    for (int m = 0; m < 4; ++m)
#pragma unroll
      for (int ks = 0; ks < 2; ++ks)
        acc[m][0] = __builtin_amdgcn_mfma_f32_16x16x32_bf16(af[m][ks], bfr[0][ks],
                                                            acc[m][0], 0, 0, 0);
    __builtin_amdgcn_s_setprio(0);
    // phase 1: stage next B; MFMA m0-3 x n1
    if (t + 1 < T) stageB(t + 1, (t + 1) & 1);
    __builtin_amdgcn_s_barrier();
    __builtin_amdgcn_s_setprio(1);
#pragma unroll
    for (int m = 0; m < 4; ++m)
#pragma unroll
      for (int ks = 0; ks < 2; ++ks)
        acc[m][1] = __builtin_amdgcn_mfma_f32_16x16x32_bf16(af[m][ks], bfr[1][ks],
                                                            acc[m][1], 0, 0, 0);
    __builtin_amdgcn_s_setprio(0);
    // phase 2: read A m4-7; MFMA m4-7 x n0
#pragma unroll
    for (int m = 0; m < 4; ++m)
#pragma unroll
      for (int ks = 0; ks < 2; ++ks)
        af[m][ks] = *(const bf16x8*)(Abuf + (arow_base + (m + 4) * 16) * 64 +
                                     (((ks * 4 + lgrp) ^ aswz) << 3));
    __builtin_amdgcn_s_barrier();
    __builtin_amdgcn_s_setprio(1);
#pragma unroll
    for (int m = 0; m < 4; ++m)
#pragma unroll
      for (int ks = 0; ks < 2; ++ks)
        acc[m + 4][0] = __builtin_amdgcn_mfma_f32_16x16x32_bf16(af[m][ks], bfr[0][ks],
                                                                acc[m + 4][0], 0, 0, 0);
    __builtin_amdgcn_s_setprio(0);
    // phase 3: MFMA m4-7 x n1
    __builtin_amdgcn_s_barrier();
    __builtin_amdgcn_s_setprio(1);
#pragma unroll
    for (int m = 0; m < 4; ++m)
#pragma unroll
      for (int ks = 0; ks < 2; ++ks)
        acc[m + 4][1] = __builtin_amdgcn_mfma_f32_16x16x32_bf16(af[m][ks], bfr[1][ks],
                                                                acc[m + 4][1], 0, 0, 0);
    __builtin_amdgcn_s_setprio(0);
    if (t + 1 < T) {
      asm volatile("s_waitcnt vmcnt(0)" ::: "memory");
      __builtin_amdgcn_s_barrier();
      __builtin_amdgcn_sched_barrier(0);
    }
  }

  float* C = Cout + (size_t)bz * zoff;
#pragma unroll
  for (int m = 0; m < 8; ++m) {
#pragma unroll
    for (int n = 0; n < 2; ++n) {
      const int row0 = mrow + wr * 128 + m * 16 + lgrp * 4;
      const int col = ncol + wc * 32 + n * 16 + lrow;
      const float bv = (bz == 0) ? bias[col] : 0.0f;
      f32x4 v = acc[m][n];
#pragma unroll
      for (int r = 0; r < 4; r++) C[(size_t)(row0 + r) * N + col] = v[r] + bv;
    }
  }
}

// ---------------- flash attention, KV-split=2, LDS-staged K/V ----------------
__global__ __launch_bounds__(256) void k_attn_split(const u16* __restrict__ Q,
                                                    const u16* __restrict__ K,
                                                    const u16* __restrict__ Vt,
                                                    float* __restrict__ Opart,
                                                    float* __restrict__ ml) {
  __shared__ __align__(16) u16 Kl[2][4096];
  __shared__ __align__(16) u16 Vl[2][4096];
  const int tid = threadIdx.x, wid = tid >> 6, lane = tid & 63;
  const int ql = lane & 31, hi = lane >> 5;
  const int bx = blockIdx.x;
  const int split = bx >> 9, bh = (bx >> 4) & 31, qblk = bx & 15;
  const int qbase = qblk * 128 + wid * 32;
  const int kvS = split * 1024;
  const u16* Qh = Q + (size_t)bh * SS * HD;
  const u16* Kh = K + (size_t)bh * SS * HD;
  const u16* Vh = Vt + (size_t)bh * HD * SS;

  const int lrow3 = lane >> 3;
  const int lin = lrow3 * 128 + ((((lane & 7) << 4)) ^ (lrow3 << 4));
  const int kswz = (ql & 7) << 4;

  auto stage = [&](int kv0, int bufi) {
    const char* Ks = (const char*)Kh + (size_t)kv0 * 128 + wid * 2048 + lin;
    const char* Vs = (const char*)Vh + ((size_t)(kv0 >> 6)) * 8192 + wid * 2048 + lin;
    char* kd = (char*)&Kl[bufi][0] + wid * 2048;
    char* vd = (char*)&Vl[bufi][0] + wid * 2048;
    gload_lds16(Ks, kd);
    gload_lds16(Ks + 1024, kd + 1024);
    gload_lds16(Vs, vd);
    gload_lds16(Vs + 1024, vd + 1024);
  };

  bf16x8 qf[4];
#pragma unroll
  for (int j = 0; j < 4; j++)
    qf[j] = *(const bf16x8*)&Qh[(size_t)(qbase + ql) * HD + j * 16 + hi * 8];

  f32x16 oacc0, oacc1;
#pragma unroll
  for (int r = 0; r < 16; r++) { oacc0[r] = 0.f; oacc1[r] = 0.f; }
  float m2 = -1e30f;
  float lsum = 0.f;
  const float cs = 0.125f * 1.44269504f;

  auto tileC = [&](int bufi, int tt) {
    const char* Kb = (const char*)&Kl[bufi][0];
    const char* Vb = (const char*)&Vl[bufi][0];
    bf16x8 kf[4];
#pragma unroll
    for (int j = 0; j < 4; j++)
      kf[j] = *(const bf16x8*)(Kb + (tt * 32 + ql) * 128 + ((j * 32 + hi * 16) ^ kswz));

    f32x16 s;
#pragma unroll
    for (int r = 0; r < 16; r++) s[r] = 0.f;
#pragma unroll
    for (int j = 0; j < 4; j++)
      s = __builtin_amdgcn_mfma_f32_32x32x16_bf16(kf[j], qf[j], s, 0, 0, 0);

    float t0 = fmaxf(fmaxf(s[0], s[1]), fmaxf(s[2], s[3]));
    float t1 = fmaxf(fmaxf(s[4], s[5]), fmaxf(s[6], s[7]));
    float t2 = fmaxf(fmaxf(s[8], s[9]), fmaxf(s[10], s[11]));
    float t3 = fmaxf(fmaxf(s[12], s[13]), fmaxf(s[14], s[15]));
    float tmax = cross32_reduce_max(fmaxf(fmaxf(t0, t1), fmaxf(t2, t3))) * cs;

    if (!__all(tmax - m2 <= 8.f)) {
      float m2n = fmaxf(m2, tmax);
      float al = exp2_(m2 - m2n);
      m2 = m2n;
      lsum *= al;
#pragma unroll
      for (int r = 0; r < 16; r++) { oacc0[r] *= al; oacc1[r] *= al; }
    }

    float p[16];
    float ts = 0.f;
#pragma unroll
    for (int r = 0; r < 16; r++) {
      p[r] = exp2_(fmaf(s[r], cs, -m2));
      ts += p[r];
    }
    lsum += cross32_reduce_sum(ts);

    u32 w01 = cvt_pk_bf16(p[0], p[1]), w23 = cvt_pk_bf16(p[2], p[3]);
    u32 w45 = cvt_pk_bf16(p[4], p[5]), w67 = cvt_pk_bf16(p[6], p[7]);
    u32 w89 = cvt_pk_bf16(p[8], p[9]), wab = cvt_pk_bf16(p[10], p[11]);
    u32 wcd = cvt_pk_bf16(p[12], p[13]), wef = cvt_pk_bf16(p[14], p[15]);
    lane32_swap(w01, w45);
    lane32_swap(w23, w67);
    lane32_swap(w89, wcd);
    lane32_swap(wab, wef);
    union { u32 w[4]; bf16x8 v; } f0, f1;
    f0.w[0] = w01; f0.w[1] = w23; f0.w[2] = w45; f0.w[3] = w67;
    f1.w[0] = w89; f1.w[1] = wab; f1.w[2] = wcd; f1.w[3] = wef;

    bf16x8 vf[4];
#pragma unroll
    for (int u = 0; u < 4; u++)
      vf[u] = *(const bf16x8*)(Vb + ((u >> 1) * 32 + ql) * 128 +
                               ((tt * 64 + (u & 1) * 32 + hi * 16) ^ kswz));

    oacc0 = __builtin_amdgcn_mfma_f32_32x32x16_bf16(vf[0], f0.v, oacc0, 0, 0, 0);
    oacc0 = __builtin_amdgcn_mfma_f32_32x32x16_bf16(vf[1], f1.v, oacc0, 0, 0, 0);
    oacc1 = __builtin_amdgcn_mfma_f32_32x32x16_bf16(vf[2], f0.v, oacc1, 0, 0, 0);
    oacc1 = __builtin_amdgcn_mfma_f32_32x32x16_bf16(vf[3], f1.v, oacc1, 0, 0, 0);
  };

  stage(kvS, 0);
  __syncthreads();
  int cur = 0;
  for (int it = 0; it < 16; ++it) {
    if (it + 1 < 16) stage(kvS + (it + 1) * 64, cur ^ 1);
    tileC(cur, 0);
    tileC(cur, 1);
    __syncthreads();
    cur ^= 1;
  }

  const int rowidx = bh * SS + qbase + ql;
  float* Orow = Opart + ((size_t)split * 32 * SS + rowidx) * HD;
  auto storeAcc = [&](const f32x16& a, int dbase) {
#pragma unroll
    for (int t = 0; t < 4; t++)
      *(float4*)&Orow[dbase + 4 * hi + 8 * t] =
          make_float4(a[4 * t], a[4 * t + 1], a[4 * t + 2], a[4 * t + 3]);
  };
  storeAcc(oacc0, 0);
  storeAcc(oacc1, 32);
  if (hi == 0)
    *(float2*)&ml[((size_t)split * 32 * SS + rowidx) * 2] = make_float2(m2, lsum);
}

// ---------------- merge the two KV-split partials -> bf16 O [T][DM] ----------------
__global__ __launch_bounds__(256) void k_attn_merge(const float* __restrict__ Opart,
                                                    const float* __restrict__ ml,
                                                    u16* __restrict__ O) {
  const int g = blockIdx.x * 256 + threadIdx.x;
  const int row = g >> 4, dseg = g & 15;
  const float2 m0 = ((const float2*)ml)[row];
  const float2 m1 = ((const float2*)ml)[32 * SS + row];
  const float mm = fmaxf(m0.x, m1.x);
  const float w0 = exp2f(m0.x - mm), w1 = exp2f(m1.x - mm);
  const float inv = 1.0f / (m0.y * w0 + m1.y * w1);
  const float4 o0 = ((const float4*)Opart)[(size_t)row * 16 + dseg];
  const float4 o1 = ((const float4*)Opart)[(size_t)(32 * SS + row) * 16 + dseg];
  const float a = (o0.x * w0 + o1.x * w1) * inv;
  const float b = (o0.y * w0 + o1.y * w1) * inv;
  const float c = (o0.z * w0 + o1.z * w1) * inv;
  const float d = (o0.w * w0 + o1.w * w1) * inv;
  const int bh = row >> 11, s = row & 2047;
  const int bb = bh >> 4, h = bh & 15;
  u64 pk = (u64)f2bf(a) | ((u64)f2bf(b) << 16) | ((u64)f2bf(c) << 32) | ((u64)f2bf(d) << 48);
  *(u64*)&O[((size_t)(bb * SS + s) * DM) + h * HD + dseg * 4] = pk;
}

// ---------------- fused residual(2-way) + layernorm ----------------
template <bool WB>
__global__ __launch_bounds__(256) void k_res_ln(const float* __restrict__ X,
                                                const float* __restrict__ Y0,
                                                const float* __restrict__ Y1,
                                                const float* __restrict__ gw,
                                                const float* __restrict__ bw,
                                                float* __restrict__ outf,
                                                u16* __restrict__ outb) {
  const int row = blockIdx.x, t = threadIdx.x;
  const float4 xv = ((const float4*)(X + (size_t)row * DM))[t];
  const float4 y0 = ((const float4*)(Y0 + (size_t)row * DM))[t];
  const float4 y1 = ((const float4*)(Y1 + (size_t)row * DM))[t];
  float v0 = xv.x + y0.x + y1.x, v1 = xv.y + y0.y + y1.y;
  float v2 = xv.z + y0.z + y1.z, v3 = xv.w + y0.w + y1.w;
  float s = v0 + v1 + v2 + v3;
  float s2 = v0 * v0 + v1 * v1 + v2 * v2 + v3 * v3;
#pragma unroll
  for (int off = 32; off >= 1; off >>= 1) {
    s += __shfl_down(s, off);
    s2 += __shfl_down(s2, off);
  }
  __shared__ float ps[4], ps2[4];
  const int wid = t >> 6, lane = t & 63;
  if (lane == 0) { ps[wid] = s; ps2[wid] = s2; }
  __syncthreads();
  const float ts = ps[0] + ps[1] + ps[2] + ps[3];
  const float ts2 = ps2[0] + ps2[1] + ps2[2] + ps2[3];
  const float mu = ts * (1.f / 1024.f);
  const float rs = rsqrtf(ts2 * (1.f / 1024.f) - mu * mu + 1e-5f);
  const float4 g4 = ((const float4*)gw)[t];
  const float4 b4 = ((const float4*)bw)[t];
  float o0 = (v0 - mu) * rs * g4.x + b4.x;
  float o1 = (v1 - mu) * rs * g4.y + b4.y;
  float o2 = (v2 - mu) * rs * g4.z + b4.z;
  float o3 = (v3 - mu) * rs * g4.w + b4.w;
  ((float4*)(outf + (size_t)row * DM))[t] = make_float4(o0, o1, o2, o3);
  if constexpr (WB) {
    u64 pk = (u64)f2bf(o0) | ((u64)f2bf(o1) << 16) | ((u64)f2bf(o2) << 32) |
             ((u64)f2bf(o3) << 48);
    ((u64*)(outb + (size_t)row * DM))[t] = pk;
  }
}

extern "C" void kernel_launch(void* const* d_in, const int* in_sizes, int n_in,
                              void* d_out, int out_size, void* d_ws, size_t ws_size,
                              hipStream_t stream) {
  const float* x = (const float*)d_in[0];
  const float* Wq = (const float*)d_in[1];
  const float* bq = (const float*)d_in[2];
  const float* Wk = (const float*)d_in[3];
  const float* bk = (const float*)d_in[4];
  const float* Wv = (const float*)d_in[5];
  const float* bv = (const float*)d_in[6];
  const float* Wo = (const float*)d_in[7];
  const float* bo = (const float*)d_in[8];
  const float* g1 = (const float*)d_in[9];
  const float* b1 = (const float*)d_in[10];
  const float* g2 = (const float*)d_in[11];
  const float* b2 = (const float*)d_in[12];
  const float* W1 = (const float*)d_in[13];
  const float* bf1 = (const float*)d_in[14];
  const float* W2 = (const float*)d_in[15];
  const float* bf2 = (const float*)d_in[16];
  float* out = (float*)d_out;

  if (ws_size < 99 * MiB) return;
  char* ws = (char*)d_ws;
  u16* WqkvT = (u16*)(ws + OFF_WQKVT);
  u16* WoT = (u16*)(ws + OFF_WOT);
  u16* W1T = (u16*)(ws + OFF_W1T);
  u16* W2T = (u16*)(ws + OFF_W2T);
  u16* xb = (u16*)(ws + OFF_XB);
  u16* Qb = (u16*)(ws + OFF_QB);
  u16* Kb = (u16*)(ws + OFF_KB);
  u16* Vt = (u16*)(ws + OFF_VT);
  u16* Ob = (u16*)(ws + OFF_XB);
  float* Opart = (float*)(ws + OFF_OPART);
  float* ml = (float*)(ws + OFF_ML);
  float* bqkv = (float*)(ws + OFF_BQKV);
  float* attn0 = (float*)(ws + OFF_OPART);
  float* attn1 = (float*)(ws + OFF_ATTN1);
  float* hf = (float*)(ws + OFF_QB);
  u16* hb = (u16*)(ws + OFF_VT);
  u16* f1 = (u16*)(ws + OFF_OPART);
  float* ffn0 = (float*)(ws + OFF_FFN0P);
  float* ffn1 = (float*)(ws + OFF_FFN1P);

  k_cast<<<4096, 256, 0, stream>>>(x, xb, TT * DM / 4);
  k_transpose_cast<<<dim3(32, 32), 256, 0, stream>>>(Wq, WqkvT, DM, DM);
  k_transpose_cast<<<dim3(32, 32), 256, 0, stream>>>(Wk, WqkvT + 1024 * 1024, DM, DM);
  k_transpose_cast<<<dim3(32, 32), 256, 0, stream>>>(Wv, WqkvT + 2048 * 1024, DM, DM);
  k_transpose_cast<<<dim3(32, 32), 256, 0, stream>>>(Wo, WoT, DM, DM);
  k_transpose_cast<<<dim3(128, 32), 256, 0, stream>>>(W1, W1T, DM, DFF);
  k_transpose_cast<<<dim3(32, 128), 256, 0, stream>>>(W2, W2T, DFF, DM);
  k_concat3<<<12, 256, 0, stream>>>(bq, bk, bv, bqkv);

  // fused QKV projection: 256^2 tiles, grid 12x16 = 192 (%8==0)
  k_gemm256<EPI_QKV3><<<192, 512, 0, stream>>>(xb, WqkvT, bqkv, ws, 3072, DM, 12);

  k_attn_split<<<1024, 256, 0, stream>>>(Qb, Kb, Vt, Opart, ml);
  k_attn_merge<<<4096, 256, 0, stream>>>(Opart, ml, Ob);

  // Wo projection: 256x128 tiles, split-K=2 -> grid 8*16*2 = 256
  k_gemmMN<<<256, 512, 0, stream>>>(Ob, WoT, bo, attn0, DM, DM / 2, DM,
                                    (size_t)TT * DM, 8, 16);
  k_res_ln<true><<<4096, 256, 0, stream>>>(x, attn0, attn1, g1, b1, hf, hb);

  // FFN1: 256^2 tiles, grid 16x16 = 256
  k_gemm256<EPI_GELU><<<256, 512, 0, stream>>>(hb, W1T, bf1, f1, DFF, DM, 16);

  // FFN2: 256x128 tiles, split-K=2 -> grid 8*16*2 = 256
  k_gemmMN<<<256, 512, 0, stream>>>(f1, W2T, bf2, ffn0, DM, DFF / 2, DFF,
                                    OFF_FFN1P / 4, 8, 16);
  k_res_ln<false><<<4096, 256, 0, stream>>>(hf, ffn0, ffn1, g2, b2, out, nullptr);
}